// Round 13
// baseline (207.305 us; speedup 1.0000x reference)
//
#include <hip/hip_runtime.h>
#include <hip/hip_bf16.h>

// ---------------- problem constants ----------------
#define F_IN   256
#define DIM    128
#define NCLS   16
#define BSH    10          // bucket shift: 1024 nodes per bucket
#define NBMAX  128         // max buckets (N<=131072)
#define CAP    20480       // per-bucket pairs capacity (expected ~16.3K, +32 sigma)
#define PCAP   28672       // per-bucket padded col region (CAP + 8*1024 worst-case pad)

typedef short bf16x8 __attribute__((ext_vector_type(8)));
typedef float f32x4  __attribute__((ext_vector_type(4)));
typedef float f32x2  __attribute__((ext_vector_type(2)));

__device__ __forceinline__ unsigned short f2bf(float f) {
    union { float f; unsigned u; } v; v.f = f;
    unsigned r = v.u + 0x7fffu + ((v.u >> 16) & 1u);   // RNE
    return (unsigned short)(r >> 16);
}
__device__ __forceinline__ float bflo(unsigned v) { return __uint_as_float(v << 16); }
__device__ __forceinline__ float bfhi(unsigned v) { return __uint_as_float(v & 0xffff0000u); }
__device__ __forceinline__ unsigned cvtpk_bf16(float lo, float hi) {
    unsigned r;
    asm("v_cvt_pk_bf16_f32 %0, %1, %2" : "=v"(r) : "v"(lo), "v"(hi));
    return r;
}

// ---------------- CSR build: fixed-capacity bucket sort, 8-padded rows ----------------

__global__ void binit_kernel(int* __restrict__ bucketCur) {
    int t = threadIdx.x;
    if (t < NBMAX) bucketCur[t] = t * CAP;
}

__global__ __launch_bounds__(1024) void part_kernel(const int* __restrict__ src,
                                                    const int* __restrict__ dst,
                                                    int* __restrict__ bucketCur,
                                                    int2* __restrict__ pairs, int E) {
    __shared__ int hist[NBMAX];
    __shared__ int pos[NBMAX];
    int t = threadIdx.x;
    int base = blockIdx.x * 8192;
    int s[8], d[8];
#pragma unroll
    for (int k = 0; k < 8; k++) {
        int i = base + k * 1024 + t;
        bool v = (i < E);
        s[k] = v ? src[i] : 0;
        d[k] = v ? dst[i] : -1;
    }
    if (t < NBMAX) hist[t] = 0;
    __syncthreads();
#pragma unroll
    for (int k = 0; k < 8; k++)
        if (d[k] >= 0) atomicAdd(&hist[d[k] >> BSH], 1);
    __syncthreads();
    if (t < NBMAX && hist[t]) pos[t] = atomicAdd(&bucketCur[t], hist[t]);
    __syncthreads();
#pragma unroll
    for (int k = 0; k < 8; k++)
        if (d[k] >= 0) {
            int p = atomicAdd(&pos[d[k] >> BSH], 1);
            pairs[p] = make_int2(s[k], d[k]);
        }
}

// one block per bucket: per-node counts, 8-padded local scan -> rowInfo/dinv,
// LDS-cursor scatter -> col, dummy-pad the slack. col region for bucket b = [b*PCAP, ...)
__global__ __launch_bounds__(256) void csr_kernel(const int2* __restrict__ pairs,
                                                  const int* __restrict__ bucketCur,
                                                  int* __restrict__ rowInfo, float* __restrict__ dinv,
                                                  int* __restrict__ col, int N) {
    __shared__ int cnt[1024];
    __shared__ int part[256];
    int b = blockIdx.x, t = threadIdx.x;
    int n0 = b << BSH;
    int nn = N - n0; if (nn > 1024) nn = 1024;
    int in0 = b * CAP;
    int inEnd = bucketCur[b];          // absolute end cursor
    int out0 = b * PCAP;

    for (int i = t; i < 1024; i += 256) cnt[i] = 0;
    __syncthreads();
    for (int p = in0 + t; p < inEnd; p += 256)
        atomicAdd(&cnt[pairs[p].y - n0], 1);
    __syncthreads();

    int i0 = t * 4;
    int c0 = cnt[i0], c1 = cnt[i0 + 1], c2 = cnt[i0 + 2], c3 = cnt[i0 + 3];
    int p0 = (c0 + 7) & ~7, p1 = (c1 + 7) & ~7, p2 = (c2 + 7) & ~7, p3 = (c3 + 7) & ~7;
    int tsum = p0 + p1 + p2 + p3;
    part[t] = tsum;
    __syncthreads();
    for (int off = 1; off < 256; off <<= 1) {
        int u = (t >= off) ? part[t - off] : 0;
        __syncthreads();
        part[t] += u;
        __syncthreads();
    }
    int run = out0 + part[t] - tsum;   // padded exclusive start for node i0
    int e0 = run, e1 = e0 + p0, e2 = e1 + p1, e3 = e2 + p2;
    __syncthreads();
    // rowInfo = (start>>3)<<12 | nchunks   (start < 3.7M, nchunks < 4096)
    if (i0 + 0 < nn) { rowInfo[n0 + i0 + 0] = ((e0 >> 3) << 12) | (p0 >> 3); dinv[n0 + i0 + 0] = rsqrtf((float)(c0 + 1)); }
    if (i0 + 1 < nn) { rowInfo[n0 + i0 + 1] = ((e1 >> 3) << 12) | (p1 >> 3); dinv[n0 + i0 + 1] = rsqrtf((float)(c1 + 1)); }
    if (i0 + 2 < nn) { rowInfo[n0 + i0 + 2] = ((e2 >> 3) << 12) | (p2 >> 3); dinv[n0 + i0 + 2] = rsqrtf((float)(c2 + 1)); }
    if (i0 + 3 < nn) { rowInfo[n0 + i0 + 3] = ((e3 >> 3) << 12) | (p3 >> 3); dinv[n0 + i0 + 3] = rsqrtf((float)(c3 + 1)); }
    cnt[i0] = e0; cnt[i0 + 1] = e1; cnt[i0 + 2] = e2; cnt[i0 + 3] = e3;   // cursors
    __syncthreads();

    for (int p = in0 + t; p < inEnd; p += 256) {
        int2 e = pairs[p];
        int q = atomicAdd(&cnt[e.y - n0], 1);
        col[q] = e.x;
    }
    __syncthreads();
    // fill padding slack with dummy node N (zero row)
    if (i0 + 0 < nn) for (int q = c0; q < p0; q++) col[e0 + q] = N;
    if (i0 + 1 < nn) for (int q = c1; q < p1; q++) col[e1 + q] = N;
    if (i0 + 2 < nn) for (int q = c2; q < p2; q++) col[e2 + q] = N;
    if (i0 + 3 < nn) for (int q = c3; q < p3; q++) col[e3 + q] = N;
}

// ---------------- W1 repack + dummy-row zeroing ----------------
__global__ void w1prep_kernel(const float* __restrict__ W1, unsigned short* __restrict__ W1f,
                              unsigned* __restrict__ h1dummy, unsigned* __restrict__ h2dummy) {
    int t = blockIdx.x * blockDim.x + threadIdx.x;
    if (blockIdx.x == 0) {
        if (threadIdx.x < 32) h1dummy[threadIdx.x] = 0;           // 128 B
        else if (threadIdx.x < 40) h2dummy[threadIdx.x - 32] = 0; // 32 B
    }
    if (t >= 8 * 32 * 16 * 8) return;
    int j = t & 7, c = (t >> 3) & 15, g = (t >> 7) & 31, f = t >> 12;
    W1f[t] = f2bf(W1[(g * 8 + j) * DIM + f * 16 + c]);
}

// ---------------- GEMM1: H1 = fp8(dinv * (X @ W1)), permuted row layout ----------------
// byte p = lr*8+f holds feature (p&7)*16 + (p>>3); lane stores 8 contiguous bytes.
__global__ __launch_bounds__(256) void gemm1_mfma(const float* __restrict__ X,
                                                  const unsigned short* __restrict__ W1f,
                                                  const float* __restrict__ dinv,
                                                  unsigned char* __restrict__ H1, int M) {
    int tid = threadIdx.x;
    int wm = tid >> 6, l = tid & 63;
    int lr = l & 15, lg = l >> 4;
    int bm = blockIdx.x * 128 + wm * 32;

    f32x4 acc[2][8];
#pragma unroll
    for (int mi = 0; mi < 2; mi++)
#pragma unroll
        for (int f = 0; f < 8; f++) acc[mi][f] = (f32x4){0.f, 0.f, 0.f, 0.f};

#pragma unroll
    for (int s = 0; s < 8; s++) {            // k-step of 32
        bf16x8 a[2];
#pragma unroll
        for (int mi = 0; mi < 2; mi++) {
            int r = bm + mi * 16 + lr;
            r = (r < M) ? r : (M - 1);
            const float* xp = X + (size_t)r * F_IN + s * 32 + lg * 8;
            float4 u0 = *(const float4*)xp;
            float4 u1 = *(const float4*)(xp + 4);
            union { uint4 w; bf16x8 v; } cv;
            cv.w.x = cvtpk_bf16(u0.x, u0.y);
            cv.w.y = cvtpk_bf16(u0.z, u0.w);
            cv.w.z = cvtpk_bf16(u1.x, u1.y);
            cv.w.w = cvtpk_bf16(u1.z, u1.w);
            a[mi] = cv.v;
        }
#pragma unroll
        for (int f = 0; f < 8; f++) {
            const unsigned short* bp = W1f + ((((f * 32 + s * 4 + lg) * 16) + lr) << 3);
            bf16x8 b = *(const bf16x8*)bp;
            acc[0][f] = __builtin_amdgcn_mfma_f32_16x16x32_bf16(a[0], b, acc[0][f], 0, 0, 0);
            acc[1][f] = __builtin_amdgcn_mfma_f32_16x16x32_bf16(a[1], b, acc[1][f], 0, 0, 0);
        }
    }
#pragma unroll
    for (int mi = 0; mi < 2; mi++) {
#pragma unroll
        for (int r = 0; r < 4; r++) {
            int row = bm + mi * 16 + lg * 4 + r;
            if (row < M) {
                float di = dinv[row];
                float v0 = di * acc[mi][0][r], v1 = di * acc[mi][1][r];
                float v2 = di * acc[mi][2][r], v3 = di * acc[mi][3][r];
                float v4 = di * acc[mi][4][r], v5 = di * acc[mi][5][r];
                float v6 = di * acc[mi][6][r], v7 = di * acc[mi][7][r];
                int w0 = __builtin_amdgcn_cvt_pk_fp8_f32(v0, v1, 0, false);
                w0 = __builtin_amdgcn_cvt_pk_fp8_f32(v2, v3, w0, true);
                int w1 = __builtin_amdgcn_cvt_pk_fp8_f32(v4, v5, 0, false);
                w1 = __builtin_amdgcn_cvt_pk_fp8_f32(v6, v7, w1, true);
                uint2 pk; pk.x = (unsigned)w0; pk.y = (unsigned)w1;
                *(uint2*)(H1 + ((size_t)row << 7) + lr * 8) = pk;
            }
        }
    }
}

// ---------------- agg1 fused: sum(H1 fp8 rows) -> *di + b1 -> relu -> @W2 -> *di -> H2(bf16) ----------------
// TWO nodes per wave: lanes 0-31 = node A, lanes 32-63 = node B. Each half gathers its own
// node's full 128-B row (32 lanes x dword). One gather inst = 2 rows. 8 gathers in flight.
// Edge lists 8-padded with dummy node N (zero row) -> clean pipelined path only.
__global__ __launch_bounds__(256, 8) void agg1_kernel(const unsigned char* __restrict__ H1,
                                                      const int* __restrict__ rowInfo,
                                                      const int* __restrict__ col,
                                                      const float* __restrict__ dinv,
                                                      const float* __restrict__ b1,
                                                      const float* __restrict__ W2,
                                                      unsigned short* __restrict__ H2, int N) {
    __shared__ f32x4 a_lds4[8][33];            // [node-in-block][li] (pad 33 breaks 4-way bank alias)
    int tid = threadIdx.x;
    int wave = tid >> 6, lane = tid & 63;
    int half = lane >> 5, li = lane & 31;
    int d = blockIdx.x * 8 + wave * 2 + half;  // this half's node
    unsigned kb4 = (unsigned)li * 4;           // dword offset within 128-B row

    float di = 0.f;
    if (d < N) {
        di = dinv[d];
        unsigned sg = *(const unsigned*)(H1 + (((unsigned)d << 7) | kb4));   // self row
        f32x2 acc01 = __builtin_amdgcn_cvt_pk_f32_fp8((int)sg, false);
        f32x2 acc23 = __builtin_amdgcn_cvt_pk_f32_fp8((int)sg, true);

        int info = rowInfo[d];
        int jb = (info >> 12) << 3;
        int jend = jb + ((info & 0xFFF) << 3);
        int sb = half << 5;
        for (int j0 = jb; j0 < jend; j0 += 32) {
            int cnt = jend - j0; if (cnt > 32) cnt = 32;   // multiple of 8
            int eidx = col[j0 + li];           // 32 edges of THIS node per chunk
            for (int kk = 0; kk < cnt; kk += 8) {          // 8 gathers in flight
                int s0 = __shfl(eidx, sb + kk + 0);
                int s1 = __shfl(eidx, sb + kk + 1);
                int s2 = __shfl(eidx, sb + kk + 2);
                int s3 = __shfl(eidx, sb + kk + 3);
                int s4 = __shfl(eidx, sb + kk + 4);
                int s5 = __shfl(eidx, sb + kk + 5);
                int s6 = __shfl(eidx, sb + kk + 6);
                int s7 = __shfl(eidx, sb + kk + 7);
                unsigned g0 = *(const unsigned*)(H1 + (((unsigned)s0 << 7) | kb4));
                unsigned g1 = *(const unsigned*)(H1 + (((unsigned)s1 << 7) | kb4));
                unsigned g2 = *(const unsigned*)(H1 + (((unsigned)s2 << 7) | kb4));
                unsigned g3 = *(const unsigned*)(H1 + (((unsigned)s3 << 7) | kb4));
                unsigned g4 = *(const unsigned*)(H1 + (((unsigned)s4 << 7) | kb4));
                unsigned g5 = *(const unsigned*)(H1 + (((unsigned)s5 << 7) | kb4));
                unsigned g6 = *(const unsigned*)(H1 + (((unsigned)s6 << 7) | kb4));
                unsigned g7 = *(const unsigned*)(H1 + (((unsigned)s7 << 7) | kb4));
                f32x2 a0 = __builtin_amdgcn_cvt_pk_f32_fp8((int)g0, false);
                f32x2 a1 = __builtin_amdgcn_cvt_pk_f32_fp8((int)g0, true);
                f32x2 b0 = __builtin_amdgcn_cvt_pk_f32_fp8((int)g1, false);
                f32x2 b1v = __builtin_amdgcn_cvt_pk_f32_fp8((int)g1, true);
                f32x2 c0 = __builtin_amdgcn_cvt_pk_f32_fp8((int)g2, false);
                f32x2 c1 = __builtin_amdgcn_cvt_pk_f32_fp8((int)g2, true);
                f32x2 d0 = __builtin_amdgcn_cvt_pk_f32_fp8((int)g3, false);
                f32x2 d1 = __builtin_amdgcn_cvt_pk_f32_fp8((int)g3, true);
                f32x2 e0 = __builtin_amdgcn_cvt_pk_f32_fp8((int)g4, false);
                f32x2 e1 = __builtin_amdgcn_cvt_pk_f32_fp8((int)g4, true);
                f32x2 h0 = __builtin_amdgcn_cvt_pk_f32_fp8((int)g5, false);
                f32x2 h1v = __builtin_amdgcn_cvt_pk_f32_fp8((int)g5, true);
                f32x2 i0 = __builtin_amdgcn_cvt_pk_f32_fp8((int)g6, false);
                f32x2 i1 = __builtin_amdgcn_cvt_pk_f32_fp8((int)g6, true);
                f32x2 k0 = __builtin_amdgcn_cvt_pk_f32_fp8((int)g7, false);
                f32x2 k1 = __builtin_amdgcn_cvt_pk_f32_fp8((int)g7, true);
                acc01 += ((a0 + b0) + (c0 + d0)) + ((e0 + h0) + (i0 + k0));
                acc23 += ((a1 + b1v) + (c1 + d1)) + ((e1 + h1v) + (i1 + k1));
            }
        }
        int p0 = li * 4;
        // feature of permuted position p: ((p&7)<<4)|(p>>3)
        int f0 = ((p0 & 7) << 4) | (p0 >> 3);
        int f1 = (((p0 + 1) & 7) << 4) | ((p0 + 1) >> 3);
        int f2 = (((p0 + 2) & 7) << 4) | ((p0 + 2) >> 3);
        int f3 = (((p0 + 3) & 7) << 4) | ((p0 + 3) >> 3);
        f32x4 a;
        a[0] = fmaxf(fmaf(acc01.x, di, b1[f0]), 0.f);
        a[1] = fmaxf(fmaf(acc01.y, di, b1[f1]), 0.f);
        a[2] = fmaxf(fmaf(acc23.x, di, b1[f2]), 0.f);
        a[3] = fmaxf(fmaf(acc23.y, di, b1[f3]), 0.f);
        a_lds4[wave * 2 + half][li] = a;
    }
    __syncthreads();
    if (d < N) {
        int c = li & 15, kg = li >> 4;       // kg in 0..1, 64 k-positions each
        const float* a_ldsf = (const float*)a_lds4[wave * 2 + half];
        const float* w2b = W2 + kg * 128 + c;
        float p = 0.f;
#pragma unroll
        for (int i = 0; i < 64; i++) {
            // flat permuted position kg*64+i -> W2 offset ((i&7)<<8) + ((i>>3)<<4) (+kg*128 in base)
            int off = ((i & 7) << 8) + ((i >> 3) << 4);
            p = fmaf(a_ldsf[kg * 64 + i], w2b[off], p);
        }
        p += __shfl_xor(p, 16);              // combine kg halves within this half-wave
        if (li < 16) H2[(size_t)d * NCLS + c] = f2bf(p * di);
    }
}

// ---------------- agg2 + log_softmax: 8 lanes/node, 2 classes/lane, 8-padded lists ----------------
__global__ __launch_bounds__(256, 8) void agg2_kernel(const unsigned short* __restrict__ H2,
                                                      const int* __restrict__ rowInfo,
                                                      const int* __restrict__ col,
                                                      const float* __restrict__ dinv,
                                                      const float* __restrict__ b2,
                                                      float* __restrict__ OUT, int N) {
    int tid = threadIdx.x;
    int g = tid >> 3, q = tid & 7;       // 32 nodes/block, 8 lanes/node
    int d = blockIdx.x * 32 + g;
    if (d >= N) return;
    unsigned cb = (unsigned)q * 4;       // byte offset: classes 2q, 2q+1
    const char* H2b = (const char*)H2;
    float di = dinv[d];
    unsigned u = *(const unsigned*)(H2b + (((unsigned)d << 5) | cb));
    f32x2 acc; acc.x = bflo(u); acc.y = bfhi(u);
    int info = rowInfo[d];
    int jb = (info >> 12) << 3;
    int jend = jb + ((info & 0xFFF) << 3);
    for (int j = jb; j < jend; j += 8) {
        unsigned u0 = *(const unsigned*)(H2b + (((unsigned)col[j + 0] << 5) | cb));
        unsigned u1 = *(const unsigned*)(H2b + (((unsigned)col[j + 1] << 5) | cb));
        unsigned u2 = *(const unsigned*)(H2b + (((unsigned)col[j + 2] << 5) | cb));
        unsigned u3 = *(const unsigned*)(H2b + (((unsigned)col[j + 3] << 5) | cb));
        unsigned u4 = *(const unsigned*)(H2b + (((unsigned)col[j + 4] << 5) | cb));
        unsigned u5 = *(const unsigned*)(H2b + (((unsigned)col[j + 5] << 5) | cb));
        unsigned u6 = *(const unsigned*)(H2b + (((unsigned)col[j + 6] << 5) | cb));
        unsigned u7 = *(const unsigned*)(H2b + (((unsigned)col[j + 7] << 5) | cb));
        f32x2 v0; v0.x = bflo(u0); v0.y = bfhi(u0);
        f32x2 v1; v1.x = bflo(u1); v1.y = bfhi(u1);
        f32x2 v2; v2.x = bflo(u2); v2.y = bfhi(u2);
        f32x2 v3; v3.x = bflo(u3); v3.y = bfhi(u3);
        f32x2 v4; v4.x = bflo(u4); v4.y = bfhi(u4);
        f32x2 v5; v5.x = bflo(u5); v5.y = bfhi(u5);
        f32x2 v6; v6.x = bflo(u6); v6.y = bfhi(u6);
        f32x2 v7; v7.x = bflo(u7); v7.y = bfhi(u7);
        acc += ((v0 + v1) + (v2 + v3)) + ((v4 + v5) + (v6 + v7));
    }
    float l0 = fmaf(acc.x, di, b2[q * 2]);
    float l1 = fmaf(acc.y, di, b2[q * 2 + 1]);
    float m = fmaxf(l0, l1);
    m = fmaxf(m, __shfl_xor(m, 1, 8));
    m = fmaxf(m, __shfl_xor(m, 2, 8));
    m = fmaxf(m, __shfl_xor(m, 4, 8));
    float e = __expf(l0 - m) + __expf(l1 - m);
    e += __shfl_xor(e, 1, 8);
    e += __shfl_xor(e, 2, 8);
    e += __shfl_xor(e, 4, 8);
    float ls = __logf(e);
    float2 o; o.x = l0 - m - ls; o.y = l1 - m - ls;
    *(float2*)(OUT + ((size_t)d << 4) + q * 2) = o;
}

// ---------------- launch ----------------
extern "C" void kernel_launch(void* const* d_in, const int* in_sizes, int n_in,
                              void* d_out, int out_size, void* d_ws, size_t ws_size,
                              hipStream_t stream) {
    const float* x  = (const float*)d_in[0];
    const int*   ei = (const int*)d_in[1];
    const float* W1 = (const float*)d_in[2];
    const float* b1 = (const float*)d_in[3];
    const float* W2 = (const float*)d_in[4];
    const float* b2 = (const float*)d_in[5];
    float* out = (float*)d_out;

    const int N = in_sizes[0] / F_IN;    // 100000
    const int E = in_sizes[1] / 2;       // 1600000
    const int* src = ei;
    const int* dst = ei + E;
    const int nb = (N + (1 << BSH) - 1) >> BSH;   // 98 buckets

    // workspace layout (256B aligned)
    char* ws = (char*)d_ws;
    size_t off = 0;
    auto alloc = [&](size_t bytes) {
        size_t o = off;
        off += (bytes + 255) & ~(size_t)255;
        return (void*)(ws + o);
    };
    int*            bucketCur   = (int*)alloc(NBMAX * 4);
    int*            rowInfo     = (int*)alloc((size_t)N * 4);
    float*          dinv        = (float*)alloc((size_t)N * 4);
    int*            colw        = (int*)alloc((size_t)NBMAX * PCAP * 4);
    unsigned short* w1f         = (unsigned short*)alloc(32768 * 2);
    unsigned short* h2          = (unsigned short*)alloc((size_t)(N + 1) * NCLS * 2);
    // union region: pairs (NBMAX*CAP*8B) alive only until csr_kernel; h1 fp8 ((N+1)*DIM) after
    size_t uni = (size_t)NBMAX * CAP * 8;
    size_t h1b = (size_t)(N + 1) * DIM;
    if (h1b > uni) uni = h1b;
    char*           ureg        = (char*)alloc(uni);
    int2*           pairs       = (int2*)ureg;
    unsigned char*  h1          = (unsigned char*)ureg;
    (void)ws_size;

    const int gridE = (E + 8191) / 8192;   // 196

    binit_kernel<<<1, NBMAX, 0, stream>>>(bucketCur);
    part_kernel<<<gridE, 1024, 0, stream>>>(src, dst, bucketCur, pairs, E);
    csr_kernel<<<nb, 256, 0, stream>>>(pairs, bucketCur, rowInfo, dinv, colw, N);

    w1prep_kernel<<<128, 256, 0, stream>>>(W1, w1f,
                                           (unsigned*)(h1 + (size_t)N * DIM),
                                           (unsigned*)(h2 + (size_t)N * NCLS));
    gemm1_mfma<<<(N + 127) / 128, 256, 0, stream>>>(x, w1f, dinv, h1, N);
    agg1_kernel<<<(N + 7) / 8, 256, 0, stream>>>(h1, rowInfo, colw, dinv, b1, W2, h2, N);
    agg2_kernel<<<(N + 31) / 32, 256, 0, stream>>>(h2, rowInfo, colw, dinv, b2, out, N);
}

// Round 14
// 175.409 us; speedup vs baseline: 1.1818x; 1.1818x over previous
//
#include <hip/hip_runtime.h>
#include <hip/hip_bf16.h>

// ---------------- problem constants ----------------
#define F_IN   256
#define DIM    128
#define NCLS   16
#define BSH    9           // bucket shift: 512 nodes per bucket
#define NBMAX  256         // max buckets (N<=131072)
#define CAP    10240       // per-bucket pairs capacity (expected ~8.2K, +23 sigma)
#define PCAP   14336       // per-bucket padded col region (CAP + 7*512 worst-case pad)

typedef short bf16x8 __attribute__((ext_vector_type(8)));
typedef float f32x4  __attribute__((ext_vector_type(4)));
typedef float f32x2  __attribute__((ext_vector_type(2)));

__device__ __forceinline__ unsigned short f2bf(float f) {
    union { float f; unsigned u; } v; v.f = f;
    unsigned r = v.u + 0x7fffu + ((v.u >> 16) & 1u);   // RNE
    return (unsigned short)(r >> 16);
}
__device__ __forceinline__ float bflo(unsigned v) { return __uint_as_float(v << 16); }
__device__ __forceinline__ float bfhi(unsigned v) { return __uint_as_float(v & 0xffff0000u); }
__device__ __forceinline__ unsigned cvtpk_bf16(float lo, float hi) {
    unsigned r;
    asm("v_cvt_pk_bf16_f32 %0, %1, %2" : "=v"(r) : "v"(lo), "v"(hi));
    return r;
}

// ---------------- CSR build: fixed-capacity bucket sort, 8-padded rows ----------------

__global__ void binit_kernel(int* __restrict__ bucketCur) {
    int t = threadIdx.x;
    if (t < NBMAX) bucketCur[t] = t * CAP;
}

__global__ __launch_bounds__(1024) void part_kernel(const int* __restrict__ src,
                                                    const int* __restrict__ dst,
                                                    int* __restrict__ bucketCur,
                                                    int2* __restrict__ pairs, int E) {
    __shared__ int hist[NBMAX];
    __shared__ int pos[NBMAX];
    int t = threadIdx.x;
    int base = blockIdx.x * 8192;
    int s[8], d[8];
#pragma unroll
    for (int k = 0; k < 8; k++) {
        int i = base + k * 1024 + t;
        bool v = (i < E);
        s[k] = v ? src[i] : 0;
        d[k] = v ? dst[i] : -1;
    }
    if (t < NBMAX) hist[t] = 0;
    __syncthreads();
#pragma unroll
    for (int k = 0; k < 8; k++)
        if (d[k] >= 0) atomicAdd(&hist[d[k] >> BSH], 1);
    __syncthreads();
    if (t < NBMAX && hist[t]) pos[t] = atomicAdd(&bucketCur[t], hist[t]);
    __syncthreads();
#pragma unroll
    for (int k = 0; k < 8; k++)
        if (d[k] >= 0) {
            int p = atomicAdd(&pos[d[k] >> BSH], 1);
            pairs[p] = make_int2(s[k], d[k]);
        }
}

// one block per bucket (512 nodes): per-node counts, 8-padded local scan -> rowInfo/dinv,
// LDS-cursor scatter -> col, dummy-pad the slack. col region for bucket b = [b*PCAP, ...)
__global__ __launch_bounds__(256) void csr_kernel(const int2* __restrict__ pairs,
                                                  const int* __restrict__ bucketCur,
                                                  int* __restrict__ rowInfo, float* __restrict__ dinv,
                                                  int* __restrict__ col, int N) {
    __shared__ int cnt[512];
    __shared__ int part[256];
    int b = blockIdx.x, t = threadIdx.x;
    int n0 = b << BSH;
    int nn = N - n0; if (nn > 512) nn = 512;
    int in0 = b * CAP;
    int inEnd = bucketCur[b];          // absolute end cursor
    int out0 = b * PCAP;

    if (t < 256) { cnt[t] = 0; cnt[t + 256] = 0; }
    __syncthreads();
    for (int p = in0 + t; p < inEnd; p += 256)
        atomicAdd(&cnt[pairs[p].y - n0], 1);
    __syncthreads();

    int i0 = t * 2;
    int c0 = cnt[i0], c1 = cnt[i0 + 1];
    int p0 = (c0 + 7) & ~7, p1 = (c1 + 7) & ~7;
    int tsum = p0 + p1;
    part[t] = tsum;
    __syncthreads();
    for (int off = 1; off < 256; off <<= 1) {
        int u = (t >= off) ? part[t - off] : 0;
        __syncthreads();
        part[t] += u;
        __syncthreads();
    }
    int run = out0 + part[t] - tsum;   // padded exclusive start for node i0
    int e0 = run, e1 = e0 + p0;
    __syncthreads();
    // rowInfo = (start>>3)<<12 | nchunks
    if (i0 + 0 < nn) { rowInfo[n0 + i0 + 0] = ((e0 >> 3) << 12) | (p0 >> 3); dinv[n0 + i0 + 0] = rsqrtf((float)(c0 + 1)); }
    if (i0 + 1 < nn) { rowInfo[n0 + i0 + 1] = ((e1 >> 3) << 12) | (p1 >> 3); dinv[n0 + i0 + 1] = rsqrtf((float)(c1 + 1)); }
    cnt[i0] = e0; cnt[i0 + 1] = e1;    // cursors
    __syncthreads();

    for (int p = in0 + t; p < inEnd; p += 256) {
        int2 e = pairs[p];
        int q = atomicAdd(&cnt[e.y - n0], 1);
        col[q] = e.x;
    }
    __syncthreads();
    // fill padding slack with dummy node N (zero row)
    if (i0 + 0 < nn) for (int q = c0; q < p0; q++) col[e0 + q] = N;
    if (i0 + 1 < nn) for (int q = c1; q < p1; q++) col[e1 + q] = N;
}

// ---------------- W1 repack + dummy-row zeroing ----------------
__global__ void w1prep_kernel(const float* __restrict__ W1, unsigned short* __restrict__ W1f,
                              unsigned* __restrict__ h1dummy, unsigned* __restrict__ h2dummy) {
    int t = blockIdx.x * blockDim.x + threadIdx.x;
    if (blockIdx.x == 0) {
        if (threadIdx.x < 32) h1dummy[threadIdx.x] = 0;           // 128 B
        else if (threadIdx.x < 40) h2dummy[threadIdx.x - 32] = 0; // 32 B
    }
    if (t >= 8 * 32 * 16 * 8) return;
    int j = t & 7, c = (t >> 3) & 15, g = (t >> 7) & 31, f = t >> 12;
    W1f[t] = f2bf(W1[(g * 8 + j) * DIM + f * 16 + c]);
}

// ---------------- GEMM1: H1 = fp8(dinv * (X @ W1)), permuted row layout ----------------
__global__ __launch_bounds__(256) void gemm1_mfma(const float* __restrict__ X,
                                                  const unsigned short* __restrict__ W1f,
                                                  const float* __restrict__ dinv,
                                                  unsigned char* __restrict__ H1, int M) {
    int tid = threadIdx.x;
    int wm = tid >> 6, l = tid & 63;
    int lr = l & 15, lg = l >> 4;
    int bm = blockIdx.x * 128 + wm * 32;

    f32x4 acc[2][8];
#pragma unroll
    for (int mi = 0; mi < 2; mi++)
#pragma unroll
        for (int f = 0; f < 8; f++) acc[mi][f] = (f32x4){0.f, 0.f, 0.f, 0.f};

#pragma unroll
    for (int s = 0; s < 8; s++) {            // k-step of 32
        bf16x8 a[2];
#pragma unroll
        for (int mi = 0; mi < 2; mi++) {
            int r = bm + mi * 16 + lr;
            r = (r < M) ? r : (M - 1);
            const float* xp = X + (size_t)r * F_IN + s * 32 + lg * 8;
            float4 u0 = *(const float4*)xp;
            float4 u1 = *(const float4*)(xp + 4);
            union { uint4 w; bf16x8 v; } cv;
            cv.w.x = cvtpk_bf16(u0.x, u0.y);
            cv.w.y = cvtpk_bf16(u0.z, u0.w);
            cv.w.z = cvtpk_bf16(u1.x, u1.y);
            cv.w.w = cvtpk_bf16(u1.z, u1.w);
            a[mi] = cv.v;
        }
#pragma unroll
        for (int f = 0; f < 8; f++) {
            const unsigned short* bp = W1f + ((((f * 32 + s * 4 + lg) * 16) + lr) << 3);
            bf16x8 b = *(const bf16x8*)bp;
            acc[0][f] = __builtin_amdgcn_mfma_f32_16x16x32_bf16(a[0], b, acc[0][f], 0, 0, 0);
            acc[1][f] = __builtin_amdgcn_mfma_f32_16x16x32_bf16(a[1], b, acc[1][f], 0, 0, 0);
        }
    }
#pragma unroll
    for (int mi = 0; mi < 2; mi++) {
#pragma unroll
        for (int r = 0; r < 4; r++) {
            int row = bm + mi * 16 + lg * 4 + r;
            if (row < M) {
                float di = dinv[row];
                float v0 = di * acc[mi][0][r], v1 = di * acc[mi][1][r];
                float v2 = di * acc[mi][2][r], v3 = di * acc[mi][3][r];
                float v4 = di * acc[mi][4][r], v5 = di * acc[mi][5][r];
                float v6 = di * acc[mi][6][r], v7 = di * acc[mi][7][r];
                int w0 = __builtin_amdgcn_cvt_pk_fp8_f32(v0, v1, 0, false);
                w0 = __builtin_amdgcn_cvt_pk_fp8_f32(v2, v3, w0, true);
                int w1 = __builtin_amdgcn_cvt_pk_fp8_f32(v4, v5, 0, false);
                w1 = __builtin_amdgcn_cvt_pk_fp8_f32(v6, v7, w1, true);
                uint2 pk; pk.x = (unsigned)w0; pk.y = (unsigned)w1;
                *(uint2*)(H1 + ((size_t)row << 7) + lr * 8) = pk;
            }
        }
    }
}

// ---------------- agg1 fused (round-12 structure): one wave per dst node ----------------
// lanes 0-31 edge A's row (dword = 4 fp8 each), lanes 32-63 edge B's row.
// Edge lists 8-padded with dummy node N (zero row) -> clean pipelined path only.
__global__ __launch_bounds__(256, 8) void agg1_kernel(const unsigned char* __restrict__ H1,
                                                      const int* __restrict__ rowInfo,
                                                      const int* __restrict__ col,
                                                      const float* __restrict__ dinv,
                                                      const float* __restrict__ b1,
                                                      const float* __restrict__ W2,
                                                      unsigned short* __restrict__ H2, int N) {
    __shared__ f32x4 a_lds4[4][32];            // flat permuted positions: lane li holds 4li..4li+3
    int tid = threadIdx.x;
    int wave = tid >> 6, lane = tid & 63;
    int d = blockIdx.x * 4 + wave;
    int half = lane >> 5;                      // 0: edge A, 1: edge B
    int li = lane & 31;
    unsigned kb4 = (unsigned)li * 4;           // this lane's dword offset within a row

    float di = 0.f;
    if (d < N) {
        di = dinv[d];
        // self row: count once (half 0 only)
        unsigned sg = *(const unsigned*)(H1 + (((unsigned)d << 7) | kb4));
        if (half) sg = 0u;
        f32x2 acc01 = __builtin_amdgcn_cvt_pk_f32_fp8((int)sg, false);
        f32x2 acc23 = __builtin_amdgcn_cvt_pk_f32_fp8((int)sg, true);

        int info = rowInfo[d];
        int jb = (info >> 12) << 3;
        int jend = jb + ((info & 0xFFF) << 3);
        for (int j0 = jb; j0 < jend; j0 += 64) {
            int cnt = jend - j0; if (cnt > 64) cnt = 64;   // multiple of 8
            int eidx = col[j0 + lane];         // one VMEM covers up to 64 edges
            for (int kk = 0; kk < cnt; kk += 8) {          // 4 pair-gathers in flight
                int sA = __shfl(eidx, kk + 0 + half);
                int sB = __shfl(eidx, kk + 2 + half);
                int sC = __shfl(eidx, kk + 4 + half);
                int sD = __shfl(eidx, kk + 6 + half);
                unsigned gA = *(const unsigned*)(H1 + (((unsigned)sA << 7) | kb4));
                unsigned gB = *(const unsigned*)(H1 + (((unsigned)sB << 7) | kb4));
                unsigned gC = *(const unsigned*)(H1 + (((unsigned)sC << 7) | kb4));
                unsigned gD = *(const unsigned*)(H1 + (((unsigned)sD << 7) | kb4));
                f32x2 a0 = __builtin_amdgcn_cvt_pk_f32_fp8((int)gA, false);
                f32x2 a1 = __builtin_amdgcn_cvt_pk_f32_fp8((int)gA, true);
                f32x2 b0 = __builtin_amdgcn_cvt_pk_f32_fp8((int)gB, false);
                f32x2 b1v = __builtin_amdgcn_cvt_pk_f32_fp8((int)gB, true);
                f32x2 c0 = __builtin_amdgcn_cvt_pk_f32_fp8((int)gC, false);
                f32x2 c1 = __builtin_amdgcn_cvt_pk_f32_fp8((int)gC, true);
                f32x2 d0 = __builtin_amdgcn_cvt_pk_f32_fp8((int)gD, false);
                f32x2 d1 = __builtin_amdgcn_cvt_pk_f32_fp8((int)gD, true);
                acc01 += (a0 + b0) + (c0 + d0);
                acc23 += (a1 + b1v) + (c1 + d1);
            }
        }
        // combine halves
        acc01.x += __shfl_xor(acc01.x, 32);
        acc01.y += __shfl_xor(acc01.y, 32);
        acc23.x += __shfl_xor(acc23.x, 32);
        acc23.y += __shfl_xor(acc23.y, 32);
        if (half == 0) {
            int p0 = li * 4;
            // feature of permuted position p: ((p&7)<<4)|(p>>3)
            int f0 = ((p0 & 7) << 4) | (p0 >> 3);
            int f1 = (((p0 + 1) & 7) << 4) | ((p0 + 1) >> 3);
            int f2 = (((p0 + 2) & 7) << 4) | ((p0 + 2) >> 3);
            int f3 = (((p0 + 3) & 7) << 4) | ((p0 + 3) >> 3);
            f32x4 a;
            a[0] = fmaxf(fmaf(acc01.x, di, b1[f0]), 0.f);
            a[1] = fmaxf(fmaf(acc01.y, di, b1[f1]), 0.f);
            a[2] = fmaxf(fmaf(acc23.x, di, b1[f2]), 0.f);
            a[3] = fmaxf(fmaf(acc23.y, di, b1[f3]), 0.f);
            a_lds4[wave][li] = a;
        }
    }
    __syncthreads();
    if (d < N) {
        int c = lane & 15, kg = lane >> 4;
        const float* a_ldsf = (const float*)a_lds4[wave];
        const float* w2b = W2 + kg * 64 + c;   // base for f = kg*4 + ...
        float p = 0.f;
#pragma unroll
        for (int i = 0; i < 32; i++) {
            // permuted position kg*32+i holds feature f = (i&7)*16 + kg*4 + (i>>3)
            int w2off = ((i & 7) << 8) + ((i >> 3) << 4);   // compile-time constant per i
            p = fmaf(a_ldsf[kg * 32 + i], w2b[w2off], p);
        }
        p += __shfl_xor(p, 16);
        p += __shfl_xor(p, 32);
        if (lane < 16) H2[(size_t)d * NCLS + c] = f2bf(p * di);
    }
}

// ---------------- agg2 + log_softmax: 8 lanes/node, 2 classes/lane, 8-padded lists ----------------
__global__ __launch_bounds__(256, 8) void agg2_kernel(const unsigned short* __restrict__ H2,
                                                      const int* __restrict__ rowInfo,
                                                      const int* __restrict__ col,
                                                      const float* __restrict__ dinv,
                                                      const float* __restrict__ b2,
                                                      float* __restrict__ OUT, int N) {
    int tid = threadIdx.x;
    int g = tid >> 3, q = tid & 7;       // 32 nodes/block, 8 lanes/node
    int d = blockIdx.x * 32 + g;
    if (d >= N) return;
    unsigned cb = (unsigned)q * 4;       // byte offset: classes 2q, 2q+1
    const char* H2b = (const char*)H2;
    float di = dinv[d];
    unsigned u = *(const unsigned*)(H2b + (((unsigned)d << 5) | cb));
    f32x2 acc; acc.x = bflo(u); acc.y = bfhi(u);
    int info = rowInfo[d];
    int jb = (info >> 12) << 3;
    int jend = jb + ((info & 0xFFF) << 3);
    for (int j = jb; j < jend; j += 8) {
        unsigned u0 = *(const unsigned*)(H2b + (((unsigned)col[j + 0] << 5) | cb));
        unsigned u1 = *(const unsigned*)(H2b + (((unsigned)col[j + 1] << 5) | cb));
        unsigned u2 = *(const unsigned*)(H2b + (((unsigned)col[j + 2] << 5) | cb));
        unsigned u3 = *(const unsigned*)(H2b + (((unsigned)col[j + 3] << 5) | cb));
        unsigned u4 = *(const unsigned*)(H2b + (((unsigned)col[j + 4] << 5) | cb));
        unsigned u5 = *(const unsigned*)(H2b + (((unsigned)col[j + 5] << 5) | cb));
        unsigned u6 = *(const unsigned*)(H2b + (((unsigned)col[j + 6] << 5) | cb));
        unsigned u7 = *(const unsigned*)(H2b + (((unsigned)col[j + 7] << 5) | cb));
        f32x2 v0; v0.x = bflo(u0); v0.y = bfhi(u0);
        f32x2 v1; v1.x = bflo(u1); v1.y = bfhi(u1);
        f32x2 v2; v2.x = bflo(u2); v2.y = bfhi(u2);
        f32x2 v3; v3.x = bflo(u3); v3.y = bfhi(u3);
        f32x2 v4; v4.x = bflo(u4); v4.y = bfhi(u4);
        f32x2 v5; v5.x = bflo(u5); v5.y = bfhi(u5);
        f32x2 v6; v6.x = bflo(u6); v6.y = bfhi(u6);
        f32x2 v7; v7.x = bflo(u7); v7.y = bfhi(u7);
        acc += ((v0 + v1) + (v2 + v3)) + ((v4 + v5) + (v6 + v7));
    }
    float l0 = fmaf(acc.x, di, b2[q * 2]);
    float l1 = fmaf(acc.y, di, b2[q * 2 + 1]);
    float m = fmaxf(l0, l1);
    m = fmaxf(m, __shfl_xor(m, 1, 8));
    m = fmaxf(m, __shfl_xor(m, 2, 8));
    m = fmaxf(m, __shfl_xor(m, 4, 8));
    float e = __expf(l0 - m) + __expf(l1 - m);
    e += __shfl_xor(e, 1, 8);
    e += __shfl_xor(e, 2, 8);
    e += __shfl_xor(e, 4, 8);
    float ls = __logf(e);
    float2 o; o.x = l0 - m - ls; o.y = l1 - m - ls;
    *(float2*)(OUT + ((size_t)d << 4) + q * 2) = o;
}

// ---------------- launch ----------------
extern "C" void kernel_launch(void* const* d_in, const int* in_sizes, int n_in,
                              void* d_out, int out_size, void* d_ws, size_t ws_size,
                              hipStream_t stream) {
    const float* x  = (const float*)d_in[0];
    const int*   ei = (const int*)d_in[1];
    const float* W1 = (const float*)d_in[2];
    const float* b1 = (const float*)d_in[3];
    const float* W2 = (const float*)d_in[4];
    const float* b2 = (const float*)d_in[5];
    float* out = (float*)d_out;

    const int N = in_sizes[0] / F_IN;    // 100000
    const int E = in_sizes[1] / 2;       // 1600000
    const int* src = ei;
    const int* dst = ei + E;
    const int nb = (N + (1 << BSH) - 1) >> BSH;   // 196 buckets

    // workspace layout (256B aligned)
    char* ws = (char*)d_ws;
    size_t off = 0;
    auto alloc = [&](size_t bytes) {
        size_t o = off;
        off += (bytes + 255) & ~(size_t)255;
        return (void*)(ws + o);
    };
    int*            bucketCur   = (int*)alloc(NBMAX * 4);
    int*            rowInfo     = (int*)alloc((size_t)N * 4);
    float*          dinv        = (float*)alloc((size_t)N * 4);
    int*            colw        = (int*)alloc((size_t)NBMAX * PCAP * 4);
    unsigned short* w1f         = (unsigned short*)alloc(32768 * 2);
    unsigned short* h2          = (unsigned short*)alloc((size_t)(N + 1) * NCLS * 2);
    // union region: pairs (NBMAX*CAP*8B) alive only until csr_kernel; h1 fp8 ((N+1)*DIM) after
    size_t uni = (size_t)NBMAX * CAP * 8;
    size_t h1b = (size_t)(N + 1) * DIM;
    if (h1b > uni) uni = h1b;
    char*           ureg        = (char*)alloc(uni);
    int2*           pairs       = (int2*)ureg;
    unsigned char*  h1          = (unsigned char*)ureg;
    (void)ws_size;

    const int gridE = (E + 8191) / 8192;   // 196

    binit_kernel<<<1, NBMAX, 0, stream>>>(bucketCur);
    part_kernel<<<gridE, 1024, 0, stream>>>(src, dst, bucketCur, pairs, E);
    csr_kernel<<<nb, 256, 0, stream>>>(pairs, bucketCur, rowInfo, dinv, colw, N);

    w1prep_kernel<<<128, 256, 0, stream>>>(W1, w1f,
                                           (unsigned*)(h1 + (size_t)N * DIM),
                                           (unsigned*)(h2 + (size_t)N * NCLS));
    gemm1_mfma<<<(N + 127) / 128, 256, 0, stream>>>(x, w1f, dinv, h1, N);
    agg1_kernel<<<(N + 3) / 4, 256, 0, stream>>>(h1, rowInfo, colw, dinv, b1, W2, h2, N);
    agg2_kernel<<<(N + 31) / 32, 256, 0, stream>>>(h2, rowInfo, colw, dinv, b2, out, N);
}

// Round 15
// 154.138 us; speedup vs baseline: 1.3449x; 1.1380x over previous
//
#include <hip/hip_runtime.h>
#include <hip/hip_bf16.h>

// ---------------- problem constants ----------------
#define F_IN   256
#define DIM    128
#define NCLS   16
#define BSH    9           // bucket shift: 512 nodes per bucket
#define NBMAX  256         // max buckets (N<=131072)
#define CAP    10240       // per-bucket pairs capacity (expected ~8.2K, +23 sigma)
#define PCAP   14336       // per-bucket padded col region (CAP + 7*512 worst-case pad)

typedef short bf16x8 __attribute__((ext_vector_type(8)));
typedef float f32x4  __attribute__((ext_vector_type(4)));
typedef float f32x2  __attribute__((ext_vector_type(2)));

__device__ __forceinline__ unsigned short f2bf(float f) {
    union { float f; unsigned u; } v; v.f = f;
    unsigned r = v.u + 0x7fffu + ((v.u >> 16) & 1u);   // RNE
    return (unsigned short)(r >> 16);
}
__device__ __forceinline__ float bflo(unsigned v) { return __uint_as_float(v << 16); }
__device__ __forceinline__ float bfhi(unsigned v) { return __uint_as_float(v & 0xffff0000u); }

// ---------------- CSR build: fixed-capacity bucket sort, 8-padded rows ----------------

__global__ void binit_kernel(int* __restrict__ bucketCur) {
    int t = threadIdx.x;
    if (t < NBMAX) bucketCur[t] = t * CAP;
}

__global__ __launch_bounds__(1024) void part_kernel(const int* __restrict__ src,
                                                    const int* __restrict__ dst,
                                                    int* __restrict__ bucketCur,
                                                    int2* __restrict__ pairs, int E) {
    __shared__ int hist[NBMAX];
    __shared__ int pos[NBMAX];
    int t = threadIdx.x;
    int base = blockIdx.x * 8192;
    int s[8], d[8];
#pragma unroll
    for (int k = 0; k < 8; k++) {
        int i = base + k * 1024 + t;
        bool v = (i < E);
        s[k] = v ? src[i] : 0;
        d[k] = v ? dst[i] : -1;
    }
    if (t < NBMAX) hist[t] = 0;
    __syncthreads();
#pragma unroll
    for (int k = 0; k < 8; k++)
        if (d[k] >= 0) atomicAdd(&hist[d[k] >> BSH], 1);
    __syncthreads();
    if (t < NBMAX && hist[t]) pos[t] = atomicAdd(&bucketCur[t], hist[t]);
    __syncthreads();
#pragma unroll
    for (int k = 0; k < 8; k++)
        if (d[k] >= 0) {
            int p = atomicAdd(&pos[d[k] >> BSH], 1);
            pairs[p] = make_int2(s[k], d[k]);
        }
}

// one block per bucket (512 nodes): per-node counts, 8-padded local scan -> rowInfo/dinv,
// LDS-cursor scatter -> col, dummy-pad the slack. col region for bucket b = [b*PCAP, ...)
__global__ __launch_bounds__(256) void csr_kernel(const int2* __restrict__ pairs,
                                                  const int* __restrict__ bucketCur,
                                                  int* __restrict__ rowInfo, float* __restrict__ dinv,
                                                  int* __restrict__ col, int N) {
    __shared__ int cnt[512];
    __shared__ int part[256];
    int b = blockIdx.x, t = threadIdx.x;
    int n0 = b << BSH;
    int nn = N - n0; if (nn > 512) nn = 512;
    int in0 = b * CAP;
    int inEnd = bucketCur[b];          // absolute end cursor
    int out0 = b * PCAP;

    if (t < 256) { cnt[t] = 0; cnt[t + 256] = 0; }
    __syncthreads();
    for (int p = in0 + t; p < inEnd; p += 256)
        atomicAdd(&cnt[pairs[p].y - n0], 1);
    __syncthreads();

    int i0 = t * 2;
    int c0 = cnt[i0], c1 = cnt[i0 + 1];
    int p0 = (c0 + 7) & ~7, p1 = (c1 + 7) & ~7;
    int tsum = p0 + p1;
    part[t] = tsum;
    __syncthreads();
    for (int off = 1; off < 256; off <<= 1) {
        int u = (t >= off) ? part[t - off] : 0;
        __syncthreads();
        part[t] += u;
        __syncthreads();
    }
    int run = out0 + part[t] - tsum;   // padded exclusive start for node i0
    int e0 = run, e1 = e0 + p0;
    __syncthreads();
    // rowInfo = (start>>3)<<12 | nchunks
    if (i0 + 0 < nn) { rowInfo[n0 + i0 + 0] = ((e0 >> 3) << 12) | (p0 >> 3); dinv[n0 + i0 + 0] = rsqrtf((float)(c0 + 1)); }
    if (i0 + 1 < nn) { rowInfo[n0 + i0 + 1] = ((e1 >> 3) << 12) | (p1 >> 3); dinv[n0 + i0 + 1] = rsqrtf((float)(c1 + 1)); }
    cnt[i0] = e0; cnt[i0 + 1] = e1;    // cursors
    __syncthreads();

    for (int p = in0 + t; p < inEnd; p += 256) {
        int2 e = pairs[p];
        int q = atomicAdd(&cnt[e.y - n0], 1);
        col[q] = e.x;
    }
    __syncthreads();
    // fill padding slack with dummy node N (zero row)
    if (i0 + 0 < nn) for (int q = c0; q < p0; q++) col[e0 + q] = N;
    if (i0 + 1 < nn) for (int q = c1; q < p1; q++) col[e1 + q] = N;
}

// ---------------- W1 repack + dummy-row zeroing ----------------
__global__ void w1prep_kernel(const float* __restrict__ W1, unsigned short* __restrict__ W1f,
                              unsigned* __restrict__ h1dummy, unsigned* __restrict__ h2dummy) {
    int t = blockIdx.x * blockDim.x + threadIdx.x;
    if (blockIdx.x == 0) {
        if (threadIdx.x < 32) h1dummy[threadIdx.x] = 0;           // 128 B
        else if (threadIdx.x < 40) h2dummy[threadIdx.x - 32] = 0; // 32 B
    }
    if (t >= 8 * 32 * 16 * 8) return;
    int j = t & 7, c = (t >> 3) & 15, g = (t >> 7) & 31, f = t >> 12;
    W1f[t] = f2bf(W1[(g * 8 + j) * DIM + f * 16 + c]);
}

// ---------------- GEMM1: H1 = fp8(dinv * (X @ W1)), permuted row layout ----------------
// 16 rows per wave (64 per block) for 2x wave count vs 32-row version; f2bf scalar
// conversion (scheduler-transparent; inline-asm cvt_pk blocks load hoisting).
__global__ __launch_bounds__(256) void gemm1_mfma(const float* __restrict__ X,
                                                  const unsigned short* __restrict__ W1f,
                                                  const float* __restrict__ dinv,
                                                  unsigned char* __restrict__ H1, int M) {
    int tid = threadIdx.x;
    int wm = tid >> 6, l = tid & 63;
    int lr = l & 15, lg = l >> 4;
    int bm = blockIdx.x * 64 + wm * 16;

    f32x4 acc[8];
#pragma unroll
    for (int f = 0; f < 8; f++) acc[f] = (f32x4){0.f, 0.f, 0.f, 0.f};

#pragma unroll
    for (int s = 0; s < 8; s++) {            // k-step of 32
        int r = bm + lr;
        r = (r < M) ? r : (M - 1);
        const float* xp = X + (size_t)r * F_IN + s * 32 + lg * 8;
        float4 u0 = *(const float4*)xp;
        float4 u1 = *(const float4*)(xp + 4);
        bf16x8 a;
        a[0] = (short)f2bf(u0.x); a[1] = (short)f2bf(u0.y);
        a[2] = (short)f2bf(u0.z); a[3] = (short)f2bf(u0.w);
        a[4] = (short)f2bf(u1.x); a[5] = (short)f2bf(u1.y);
        a[6] = (short)f2bf(u1.z); a[7] = (short)f2bf(u1.w);
#pragma unroll
        for (int f = 0; f < 8; f++) {
            const unsigned short* bp = W1f + ((((f * 32 + s * 4 + lg) * 16) + lr) << 3);
            bf16x8 b = *(const bf16x8*)bp;
            acc[f] = __builtin_amdgcn_mfma_f32_16x16x32_bf16(a, b, acc[f], 0, 0, 0);
        }
    }
#pragma unroll
    for (int r = 0; r < 4; r++) {
        int row = bm + lg * 4 + r;
        if (row < M) {
            float di = dinv[row];
            float v0 = di * acc[0][r], v1 = di * acc[1][r];
            float v2 = di * acc[2][r], v3 = di * acc[3][r];
            float v4 = di * acc[4][r], v5 = di * acc[5][r];
            float v6 = di * acc[6][r], v7 = di * acc[7][r];
            int w0 = __builtin_amdgcn_cvt_pk_fp8_f32(v0, v1, 0, false);
            w0 = __builtin_amdgcn_cvt_pk_fp8_f32(v2, v3, w0, true);
            int w1 = __builtin_amdgcn_cvt_pk_fp8_f32(v4, v5, 0, false);
            w1 = __builtin_amdgcn_cvt_pk_fp8_f32(v6, v7, w1, true);
            uint2 pk; pk.x = (unsigned)w0; pk.y = (unsigned)w1;
            *(uint2*)(H1 + ((size_t)row << 7) + lr * 8) = pk;
        }
    }
}

// ---------------- agg1 fused (round-12 structure): one wave per dst node ----------------
// lanes 0-31 edge A's row (dword = 4 fp8 each), lanes 32-63 edge B's row.
// Edge lists 8-padded with dummy node N (zero row) -> clean pipelined path only.
__global__ __launch_bounds__(256, 8) void agg1_kernel(const unsigned char* __restrict__ H1,
                                                      const int* __restrict__ rowInfo,
                                                      const int* __restrict__ col,
                                                      const float* __restrict__ dinv,
                                                      const float* __restrict__ b1,
                                                      const float* __restrict__ W2,
                                                      unsigned short* __restrict__ H2, int N) {
    __shared__ f32x4 a_lds4[4][32];            // flat permuted positions: lane li holds 4li..4li+3
    int tid = threadIdx.x;
    int wave = tid >> 6, lane = tid & 63;
    int d = blockIdx.x * 4 + wave;
    int half = lane >> 5;                      // 0: edge A, 1: edge B
    int li = lane & 31;
    unsigned kb4 = (unsigned)li * 4;           // this lane's dword offset within a row

    float di = 0.f;
    if (d < N) {
        di = dinv[d];
        // self row: count once (half 0 only)
        unsigned sg = *(const unsigned*)(H1 + (((unsigned)d << 7) | kb4));
        if (half) sg = 0u;
        f32x2 acc01 = __builtin_amdgcn_cvt_pk_f32_fp8((int)sg, false);
        f32x2 acc23 = __builtin_amdgcn_cvt_pk_f32_fp8((int)sg, true);

        int info = rowInfo[d];
        int jb = (info >> 12) << 3;
        int jend = jb + ((info & 0xFFF) << 3);
        for (int j0 = jb; j0 < jend; j0 += 64) {
            int cnt = jend - j0; if (cnt > 64) cnt = 64;   // multiple of 8
            int eidx = col[j0 + lane];         // one VMEM covers up to 64 edges
            for (int kk = 0; kk < cnt; kk += 8) {          // 4 pair-gathers in flight
                int sA = __shfl(eidx, kk + 0 + half);
                int sB = __shfl(eidx, kk + 2 + half);
                int sC = __shfl(eidx, kk + 4 + half);
                int sD = __shfl(eidx, kk + 6 + half);
                unsigned gA = *(const unsigned*)(H1 + (((unsigned)sA << 7) | kb4));
                unsigned gB = *(const unsigned*)(H1 + (((unsigned)sB << 7) | kb4));
                unsigned gC = *(const unsigned*)(H1 + (((unsigned)sC << 7) | kb4));
                unsigned gD = *(const unsigned*)(H1 + (((unsigned)sD << 7) | kb4));
                f32x2 a0 = __builtin_amdgcn_cvt_pk_f32_fp8((int)gA, false);
                f32x2 a1 = __builtin_amdgcn_cvt_pk_f32_fp8((int)gA, true);
                f32x2 b0 = __builtin_amdgcn_cvt_pk_f32_fp8((int)gB, false);
                f32x2 b1v = __builtin_amdgcn_cvt_pk_f32_fp8((int)gB, true);
                f32x2 c0 = __builtin_amdgcn_cvt_pk_f32_fp8((int)gC, false);
                f32x2 c1 = __builtin_amdgcn_cvt_pk_f32_fp8((int)gC, true);
                f32x2 d0 = __builtin_amdgcn_cvt_pk_f32_fp8((int)gD, false);
                f32x2 d1 = __builtin_amdgcn_cvt_pk_f32_fp8((int)gD, true);
                acc01 += (a0 + b0) + (c0 + d0);
                acc23 += (a1 + b1v) + (c1 + d1);
            }
        }
        // combine halves
        acc01.x += __shfl_xor(acc01.x, 32);
        acc01.y += __shfl_xor(acc01.y, 32);
        acc23.x += __shfl_xor(acc23.x, 32);
        acc23.y += __shfl_xor(acc23.y, 32);
        if (half == 0) {
            int p0 = li * 4;
            // feature of permuted position p: ((p&7)<<4)|(p>>3)
            int f0 = ((p0 & 7) << 4) | (p0 >> 3);
            int f1 = (((p0 + 1) & 7) << 4) | ((p0 + 1) >> 3);
            int f2 = (((p0 + 2) & 7) << 4) | ((p0 + 2) >> 3);
            int f3 = (((p0 + 3) & 7) << 4) | ((p0 + 3) >> 3);
            f32x4 a;
            a[0] = fmaxf(fmaf(acc01.x, di, b1[f0]), 0.f);
            a[1] = fmaxf(fmaf(acc01.y, di, b1[f1]), 0.f);
            a[2] = fmaxf(fmaf(acc23.x, di, b1[f2]), 0.f);
            a[3] = fmaxf(fmaf(acc23.y, di, b1[f3]), 0.f);
            a_lds4[wave][li] = a;
        }
    }
    __syncthreads();
    if (d < N) {
        int c = lane & 15, kg = lane >> 4;
        const float* a_ldsf = (const float*)a_lds4[wave];
        const float* w2b = W2 + kg * 64 + c;   // base for f = kg*4 + ...
        float p = 0.f;
#pragma unroll
        for (int i = 0; i < 32; i++) {
            // permuted position kg*32+i holds feature f = (i&7)*16 + kg*4 + (i>>3)
            int w2off = ((i & 7) << 8) + ((i >> 3) << 4);   // compile-time constant per i
            p = fmaf(a_ldsf[kg * 32 + i], w2b[w2off], p);
        }
        p += __shfl_xor(p, 16);
        p += __shfl_xor(p, 32);
        if (lane < 16) H2[(size_t)d * NCLS + c] = f2bf(p * di);
    }
}

// ---------------- agg2 + log_softmax: 8 lanes/node, 2 classes/lane, 8-padded lists ----------------
__global__ __launch_bounds__(256, 8) void agg2_kernel(const unsigned short* __restrict__ H2,
                                                      const int* __restrict__ rowInfo,
                                                      const int* __restrict__ col,
                                                      const float* __restrict__ dinv,
                                                      const float* __restrict__ b2,
                                                      float* __restrict__ OUT, int N) {
    int tid = threadIdx.x;
    int g = tid >> 3, q = tid & 7;       // 32 nodes/block, 8 lanes/node
    int d = blockIdx.x * 32 + g;
    if (d >= N) return;
    unsigned cb = (unsigned)q * 4;       // byte offset: classes 2q, 2q+1
    const char* H2b = (const char*)H2;
    float di = dinv[d];
    unsigned u = *(const unsigned*)(H2b + (((unsigned)d << 5) | cb));
    f32x2 acc; acc.x = bflo(u); acc.y = bfhi(u);
    int info = rowInfo[d];
    int jb = (info >> 12) << 3;
    int jend = jb + ((info & 0xFFF) << 3);
    for (int j = jb; j < jend; j += 8) {
        unsigned u0 = *(const unsigned*)(H2b + (((unsigned)col[j + 0] << 5) | cb));
        unsigned u1 = *(const unsigned*)(H2b + (((unsigned)col[j + 1] << 5) | cb));
        unsigned u2 = *(const unsigned*)(H2b + (((unsigned)col[j + 2] << 5) | cb));
        unsigned u3 = *(const unsigned*)(H2b + (((unsigned)col[j + 3] << 5) | cb));
        unsigned u4 = *(const unsigned*)(H2b + (((unsigned)col[j + 4] << 5) | cb));
        unsigned u5 = *(const unsigned*)(H2b + (((unsigned)col[j + 5] << 5) | cb));
        unsigned u6 = *(const unsigned*)(H2b + (((unsigned)col[j + 6] << 5) | cb));
        unsigned u7 = *(const unsigned*)(H2b + (((unsigned)col[j + 7] << 5) | cb));
        f32x2 v0; v0.x = bflo(u0); v0.y = bfhi(u0);
        f32x2 v1; v1.x = bflo(u1); v1.y = bfhi(u1);
        f32x2 v2; v2.x = bflo(u2); v2.y = bfhi(u2);
        f32x2 v3; v3.x = bflo(u3); v3.y = bfhi(u3);
        f32x2 v4; v4.x = bflo(u4); v4.y = bfhi(u4);
        f32x2 v5; v5.x = bflo(u5); v5.y = bfhi(u5);
        f32x2 v6; v6.x = bflo(u6); v6.y = bfhi(u6);
        f32x2 v7; v7.x = bflo(u7); v7.y = bfhi(u7);
        acc += ((v0 + v1) + (v2 + v3)) + ((v4 + v5) + (v6 + v7));
    }
    float l0 = fmaf(acc.x, di, b2[q * 2]);
    float l1 = fmaf(acc.y, di, b2[q * 2 + 1]);
    float m = fmaxf(l0, l1);
    m = fmaxf(m, __shfl_xor(m, 1, 8));
    m = fmaxf(m, __shfl_xor(m, 2, 8));
    m = fmaxf(m, __shfl_xor(m, 4, 8));
    float e = __expf(l0 - m) + __expf(l1 - m);
    e += __shfl_xor(e, 1, 8);
    e += __shfl_xor(e, 2, 8);
    e += __shfl_xor(e, 4, 8);
    float ls = __logf(e);
    float2 o; o.x = l0 - m - ls; o.y = l1 - m - ls;
    *(float2*)(OUT + ((size_t)d << 4) + q * 2) = o;
}

// ---------------- launch ----------------
extern "C" void kernel_launch(void* const* d_in, const int* in_sizes, int n_in,
                              void* d_out, int out_size, void* d_ws, size_t ws_size,
                              hipStream_t stream) {
    const float* x  = (const float*)d_in[0];
    const int*   ei = (const int*)d_in[1];
    const float* W1 = (const float*)d_in[2];
    const float* b1 = (const float*)d_in[3];
    const float* W2 = (const float*)d_in[4];
    const float* b2 = (const float*)d_in[5];
    float* out = (float*)d_out;

    const int N = in_sizes[0] / F_IN;    // 100000
    const int E = in_sizes[1] / 2;       // 1600000
    const int* src = ei;
    const int* dst = ei + E;
    const int nb = (N + (1 << BSH) - 1) >> BSH;   // 196 buckets

    // workspace layout (256B aligned)
    char* ws = (char*)d_ws;
    size_t off = 0;
    auto alloc = [&](size_t bytes) {
        size_t o = off;
        off += (bytes + 255) & ~(size_t)255;
        return (void*)(ws + o);
    };
    int*            bucketCur   = (int*)alloc(NBMAX * 4);
    int*            rowInfo     = (int*)alloc((size_t)N * 4);
    float*          dinv        = (float*)alloc((size_t)N * 4);
    int*            colw        = (int*)alloc((size_t)NBMAX * PCAP * 4);
    unsigned short* w1f         = (unsigned short*)alloc(32768 * 2);
    unsigned short* h2          = (unsigned short*)alloc((size_t)(N + 1) * NCLS * 2);
    // union region: pairs (NBMAX*CAP*8B) alive only until csr_kernel; h1 fp8 ((N+1)*DIM) after
    size_t uni = (size_t)NBMAX * CAP * 8;
    size_t h1b = (size_t)(N + 1) * DIM;
    if (h1b > uni) uni = h1b;
    char*           ureg        = (char*)alloc(uni);
    int2*           pairs       = (int2*)ureg;
    unsigned char*  h1          = (unsigned char*)ureg;
    (void)ws_size;

    const int gridE = (E + 8191) / 8192;   // 196

    binit_kernel<<<1, NBMAX, 0, stream>>>(bucketCur);
    part_kernel<<<gridE, 1024, 0, stream>>>(src, dst, bucketCur, pairs, E);
    csr_kernel<<<nb, 256, 0, stream>>>(pairs, bucketCur, rowInfo, dinv, colw, N);

    w1prep_kernel<<<128, 256, 0, stream>>>(W1, w1f,
                                           (unsigned*)(h1 + (size_t)N * DIM),
                                           (unsigned*)(h2 + (size_t)N * NCLS));
    gemm1_mfma<<<(N + 63) / 64, 256, 0, stream>>>(x, w1f, dinv, h1, N);
    agg1_kernel<<<(N + 3) / 4, 256, 0, stream>>>(h1, rowInfo, colw, dinv, b1, W2, h2, N);
    agg2_kernel<<<(N + 31) / 32, 256, 0, stream>>>(h2, rowInfo, colw, dinv, b2, out, N);
}

// Round 19
// 143.610 us; speedup vs baseline: 1.4435x; 1.0733x over previous
//
#include <hip/hip_runtime.h>
#include <hip/hip_bf16.h>

// ---------------- problem constants ----------------
#define F_IN   256
#define DIM    128
#define NCLS   16
#define BSH    9           // bucket shift: 512 nodes per bucket
#define NBMAX  256         // max buckets (N<=131072)
#define CAP    10240       // per-bucket pairs capacity (expected ~8.2K, +22 sigma)
#define PCAP   18432       // per-bucket padded col region (CAP + 16*512 pad headroom)

typedef short bf16x8 __attribute__((ext_vector_type(8)));
typedef float f32x4  __attribute__((ext_vector_type(4)));
typedef float f32x2  __attribute__((ext_vector_type(2)));

__device__ __forceinline__ unsigned short f2bf(float f) {
    union { float f; unsigned u; } v; v.f = f;
    unsigned r = v.u + 0x7fffu + ((v.u >> 16) & 1u);   // RNE
    return (unsigned short)(r >> 16);
}
__device__ __forceinline__ float bflo(unsigned v) { return __uint_as_float(v << 16); }
__device__ __forceinline__ float bfhi(unsigned v) { return __uint_as_float(v & 0xffff0000u); }

// ---------------- init: bucket cursors + W1 repack + dummy rows + dinv[N]=0 ----------------
__global__ void init_kernel(const float* __restrict__ W1, unsigned short* __restrict__ W1f,
                            int* __restrict__ bucketCur,
                            unsigned* __restrict__ h1dummy, unsigned* __restrict__ h2dummy,
                            float* __restrict__ dinv, int N) {
    int t = blockIdx.x * blockDim.x + threadIdx.x;
    if (blockIdx.x == 0) {
        bucketCur[threadIdx.x] = threadIdx.x * CAP;               // NBMAX = 256 = blockDim
        if (threadIdx.x < 32) h1dummy[threadIdx.x] = 0;           // 128 B fp8 dummy row
        else if (threadIdx.x < 40) h2dummy[threadIdx.x - 32] = 0; // 32 B bf16 dummy row
        else if (threadIdx.x == 40) dinv[N] = 0.f;                // dummy dinv -> pad edges = 0
    }
    if (t >= 8 * 32 * 16 * 8) return;
    int j = t & 7, c = (t >> 3) & 15, g = (t >> 7) & 31, f = t >> 12;
    W1f[t] = f2bf(W1[(g * 8 + j) * DIM + f * 16 + c]);
}

// ---------------- part: partition edges into per-bucket capacity regions ----------------
__global__ __launch_bounds__(1024) void part_kernel(const int* __restrict__ src,
                                                    const int* __restrict__ dst,
                                                    int* __restrict__ bucketCur,
                                                    int2* __restrict__ pairs, int E) {
    __shared__ int hist[NBMAX];
    __shared__ int pos[NBMAX];
    int t = threadIdx.x;
    int base = blockIdx.x * 8192;
    int s[8], d[8];
#pragma unroll
    for (int k = 0; k < 8; k++) {
        int i = base + k * 1024 + t;
        bool v = (i < E);
        s[k] = v ? src[i] : 0;
        d[k] = v ? dst[i] : -1;
    }
    if (t < NBMAX) hist[t] = 0;
    __syncthreads();
#pragma unroll
    for (int k = 0; k < 8; k++)
        if (d[k] >= 0) atomicAdd(&hist[d[k] >> BSH], 1);
    __syncthreads();
    if (t < NBMAX && hist[t]) pos[t] = atomicAdd(&bucketCur[t], hist[t]);
    __syncthreads();
#pragma unroll
    for (int k = 0; k < 8; k++)
        if (d[k] >= 0) {
            int p = atomicAdd(&pos[d[k] >> BSH], 1);
            pairs[p] = make_int2(s[k], d[k]);
        }
}

// ---------------- fat kernel: csr (blocks 0..nbCsr-1) || gemm1 (rest) ----------------
// csr: per-node counts, 16-padded local scan -> rowInfo/dinv, LDS-cursor scatter -> col.
// gemm: H1u = fp8(X @ W1) UNSCALED (dinv applied in agg1) -> independent of csr.
__global__ __launch_bounds__(256) void csr_gemm_kernel(
        const int2* __restrict__ pairs, const int* __restrict__ bucketCur,
        int* __restrict__ rowInfo, float* __restrict__ dinv, int* __restrict__ col,
        const float* __restrict__ X, const unsigned short* __restrict__ W1f,
        unsigned char* __restrict__ H1, int N, int nbCsr) {
    __shared__ int cnt[512];
    __shared__ int part[256];
    int t = threadIdx.x;

    if (blockIdx.x < nbCsr) {
        // ---- CSR body ----
        int b = blockIdx.x;
        int n0 = b << BSH;
        int nn = N - n0; if (nn > 512) nn = 512;
        int in0 = b * CAP;
        int inEnd = bucketCur[b];
        int out0 = b * PCAP;

        cnt[t] = 0; cnt[t + 256] = 0;
        __syncthreads();
        for (int p = in0 + t; p < inEnd; p += 256)
            atomicAdd(&cnt[pairs[p].y - n0], 1);
        __syncthreads();

        int i0 = t * 2;
        int c0 = cnt[i0], c1 = cnt[i0 + 1];
        int p0 = (c0 + 15) & ~15, p1 = (c1 + 15) & ~15;   // pad to 16
        int tsum = p0 + p1;
        part[t] = tsum;
        __syncthreads();
        for (int off = 1; off < 256; off <<= 1) {
            int u = (t >= off) ? part[t - off] : 0;
            __syncthreads();
            part[t] += u;
            __syncthreads();
        }
        int run = out0 + part[t] - tsum;
        int e0 = run, e1 = e0 + p0;
        __syncthreads();
        // rowInfo = (start>>4)<<12 | nchunks16
        if (i0 + 0 < nn) { rowInfo[n0 + i0 + 0] = ((e0 >> 4) << 12) | (p0 >> 4); dinv[n0 + i0 + 0] = rsqrtf((float)(c0 + 1)); }
        if (i0 + 1 < nn) { rowInfo[n0 + i0 + 1] = ((e1 >> 4) << 12) | (p1 >> 4); dinv[n0 + i0 + 1] = rsqrtf((float)(c1 + 1)); }
        cnt[i0] = e0; cnt[i0 + 1] = e1;    // cursors
        __syncthreads();

        for (int p = in0 + t; p < inEnd; p += 256) {
            int2 e = pairs[p];
            int q = atomicAdd(&cnt[e.y - n0], 1);
            col[q] = e.x;
        }
        __syncthreads();
        if (i0 + 0 < nn) for (int q = c0; q < p0; q++) col[e0 + q] = N;   // dummy pad
        if (i0 + 1 < nn) for (int q = c1; q < p1; q++) col[e1 + q] = N;
    } else {
        // ---- GEMM body: 16 rows/wave, 64 rows/block ----
        int gb = blockIdx.x - nbCsr;
        int wm = t >> 6, l = t & 63;
        int lr = l & 15, lg = l >> 4;
        int bm = gb * 64 + wm * 16;

        f32x4 acc[8];
#pragma unroll
        for (int f = 0; f < 8; f++) acc[f] = (f32x4){0.f, 0.f, 0.f, 0.f};

#pragma unroll
        for (int s = 0; s < 8; s++) {            // k-step of 32
            int r = bm + lr;
            r = (r < N) ? r : (N - 1);
            const float* xp = X + (size_t)r * F_IN + s * 32 + lg * 8;
            float4 u0 = *(const float4*)xp;
            float4 u1 = *(const float4*)(xp + 4);
            bf16x8 a;
            a[0] = (short)f2bf(u0.x); a[1] = (short)f2bf(u0.y);
            a[2] = (short)f2bf(u0.z); a[3] = (short)f2bf(u0.w);
            a[4] = (short)f2bf(u1.x); a[5] = (short)f2bf(u1.y);
            a[6] = (short)f2bf(u1.z); a[7] = (short)f2bf(u1.w);
#pragma unroll
            for (int f = 0; f < 8; f++) {
                const unsigned short* bp = W1f + ((((f * 32 + s * 4 + lg) * 16) + lr) << 3);
                bf16x8 b = *(const bf16x8*)bp;
                acc[f] = __builtin_amdgcn_mfma_f32_16x16x32_bf16(a, b, acc[f], 0, 0, 0);
            }
        }
#pragma unroll
        for (int r = 0; r < 4; r++) {
            int row = bm + lg * 4 + r;
            if (row < N) {
                int w0 = __builtin_amdgcn_cvt_pk_fp8_f32(acc[0][r], acc[1][r], 0, false);
                w0 = __builtin_amdgcn_cvt_pk_fp8_f32(acc[2][r], acc[3][r], w0, true);
                int w1 = __builtin_amdgcn_cvt_pk_fp8_f32(acc[4][r], acc[5][r], 0, false);
                w1 = __builtin_amdgcn_cvt_pk_fp8_f32(acc[6][r], acc[7][r], w1, true);
                uint2 pk; pk.x = (unsigned)w0; pk.y = (unsigned)w1;
                *(uint2*)(H1 + ((size_t)row << 7) + lr * 8) = pk;
            }
        }
    }
}

// ---------------- agg1 fused: sum(dv_s * H1u[s]) -> *di + b1 -> relu -> @W2 -> *di -> H2(bf16) ----------------
// one wave per dst node; lanes 0-31 edge A's row (dword = 4 fp8), lanes 32-63 edge B's row.
// Rows 16-padded with dummy node N (dinv[N]=0 -> pad contributes 0). 8 pair-gathers in flight.
__global__ __launch_bounds__(256, 8) void agg1_kernel(const unsigned char* __restrict__ H1,
                                                      const int* __restrict__ rowInfo,
                                                      const int* __restrict__ col,
                                                      const float* __restrict__ dinv,
                                                      const float* __restrict__ b1,
                                                      const float* __restrict__ W2,
                                                      unsigned short* __restrict__ H2, int N) {
    __shared__ f32x4 a_lds4[4][32];
    int tid = threadIdx.x;
    int wave = tid >> 6, lane = tid & 63;
    int d = blockIdx.x * 4 + wave;
    int half = lane >> 5;
    int li = lane & 31;
    unsigned kb4 = (unsigned)li * 4;

    float di = 0.f;
    if (d < N) {
        di = dinv[d];
        unsigned sg = *(const unsigned*)(H1 + (((unsigned)d << 7) | kb4));   // self row (unscaled)
        if (half) sg = 0u;
        f32x2 s0v = __builtin_amdgcn_cvt_pk_f32_fp8((int)sg, false);
        f32x2 s1v = __builtin_amdgcn_cvt_pk_f32_fp8((int)sg, true);
        f32x2 acc01, acc23;
        acc01.x = s0v.x * di; acc01.y = s0v.y * di;
        acc23.x = s1v.x * di; acc23.y = s1v.y * di;

        int info = rowInfo[d];
        int jb = (info >> 12) << 4;
        int jend = jb + ((info & 0xFFF) << 4);
        for (int j0 = jb; j0 < jend; j0 += 64) {
            int cnt = jend - j0; if (cnt > 64) cnt = 64;   // multiple of 16
            int eidx = col[j0 + lane];         // 64 edges: one VMEM
            // clamp: tail lanes may read uninitialized (poison) col at bucket tails;
            // they are never shfl-selected for kk<cnt, but eidx is dereferenced for dv below.
            if ((unsigned)eidx > (unsigned)N) eidx = N;
            float dv = dinv[eidx];             // 64 dinv: one VMEM gather (dinv[N]=0)
            for (int kk = 0; kk < cnt; kk += 16) {         // 8 pair-gathers in flight
                int sA = __shfl(eidx, kk + 0 + half),  sB = __shfl(eidx, kk + 2 + half);
                int sC = __shfl(eidx, kk + 4 + half),  sD = __shfl(eidx, kk + 6 + half);
                int sE = __shfl(eidx, kk + 8 + half),  sF = __shfl(eidx, kk + 10 + half);
                int sG = __shfl(eidx, kk + 12 + half), sH = __shfl(eidx, kk + 14 + half);
                float vA = __shfl(dv, kk + 0 + half),  vB = __shfl(dv, kk + 2 + half);
                float vC = __shfl(dv, kk + 4 + half),  vD = __shfl(dv, kk + 6 + half);
                float vE = __shfl(dv, kk + 8 + half),  vF = __shfl(dv, kk + 10 + half);
                float vG = __shfl(dv, kk + 12 + half), vH = __shfl(dv, kk + 14 + half);
                unsigned gA = *(const unsigned*)(H1 + (((unsigned)sA << 7) | kb4));
                unsigned gB = *(const unsigned*)(H1 + (((unsigned)sB << 7) | kb4));
                unsigned gC = *(const unsigned*)(H1 + (((unsigned)sC << 7) | kb4));
                unsigned gD = *(const unsigned*)(H1 + (((unsigned)sD << 7) | kb4));
                unsigned gE = *(const unsigned*)(H1 + (((unsigned)sE << 7) | kb4));
                unsigned gF = *(const unsigned*)(H1 + (((unsigned)sF << 7) | kb4));
                unsigned gG = *(const unsigned*)(H1 + (((unsigned)sG << 7) | kb4));
                unsigned gH = *(const unsigned*)(H1 + (((unsigned)sH << 7) | kb4));
                f32x2 t0, t1;
                t0 = __builtin_amdgcn_cvt_pk_f32_fp8((int)gA, false);
                t1 = __builtin_amdgcn_cvt_pk_f32_fp8((int)gA, true);
                acc01.x = fmaf(t0.x, vA, acc01.x); acc01.y = fmaf(t0.y, vA, acc01.y);
                acc23.x = fmaf(t1.x, vA, acc23.x); acc23.y = fmaf(t1.y, vA, acc23.y);
                t0 = __builtin_amdgcn_cvt_pk_f32_fp8((int)gB, false);
                t1 = __builtin_amdgcn_cvt_pk_f32_fp8((int)gB, true);
                acc01.x = fmaf(t0.x, vB, acc01.x); acc01.y = fmaf(t0.y, vB, acc01.y);
                acc23.x = fmaf(t1.x, vB, acc23.x); acc23.y = fmaf(t1.y, vB, acc23.y);
                t0 = __builtin_amdgcn_cvt_pk_f32_fp8((int)gC, false);
                t1 = __builtin_amdgcn_cvt_pk_f32_fp8((int)gC, true);
                acc01.x = fmaf(t0.x, vC, acc01.x); acc01.y = fmaf(t0.y, vC, acc01.y);
                acc23.x = fmaf(t1.x, vC, acc23.x); acc23.y = fmaf(t1.y, vC, acc23.y);
                t0 = __builtin_amdgcn_cvt_pk_f32_fp8((int)gD, false);
                t1 = __builtin_amdgcn_cvt_pk_f32_fp8((int)gD, true);
                acc01.x = fmaf(t0.x, vD, acc01.x); acc01.y = fmaf(t0.y, vD, acc01.y);
                acc23.x = fmaf(t1.x, vD, acc23.x); acc23.y = fmaf(t1.y, vD, acc23.y);
                t0 = __builtin_amdgcn_cvt_pk_f32_fp8((int)gE, false);
                t1 = __builtin_amdgcn_cvt_pk_f32_fp8((int)gE, true);
                acc01.x = fmaf(t0.x, vE, acc01.x); acc01.y = fmaf(t0.y, vE, acc01.y);
                acc23.x = fmaf(t1.x, vE, acc23.x); acc23.y = fmaf(t1.y, vE, acc23.y);
                t0 = __builtin_amdgcn_cvt_pk_f32_fp8((int)gF, false);
                t1 = __builtin_amdgcn_cvt_pk_f32_fp8((int)gF, true);
                acc01.x = fmaf(t0.x, vF, acc01.x); acc01.y = fmaf(t0.y, vF, acc01.y);
                acc23.x = fmaf(t1.x, vF, acc23.x); acc23.y = fmaf(t1.y, vF, acc23.y);
                t0 = __builtin_amdgcn_cvt_pk_f32_fp8((int)gG, false);
                t1 = __builtin_amdgcn_cvt_pk_f32_fp8((int)gG, true);
                acc01.x = fmaf(t0.x, vG, acc01.x); acc01.y = fmaf(t0.y, vG, acc01.y);
                acc23.x = fmaf(t1.x, vG, acc23.x); acc23.y = fmaf(t1.y, vG, acc23.y);
                t0 = __builtin_amdgcn_cvt_pk_f32_fp8((int)gH, false);
                t1 = __builtin_amdgcn_cvt_pk_f32_fp8((int)gH, true);
                acc01.x = fmaf(t0.x, vH, acc01.x); acc01.y = fmaf(t0.y, vH, acc01.y);
                acc23.x = fmaf(t1.x, vH, acc23.x); acc23.y = fmaf(t1.y, vH, acc23.y);
            }
        }
        // combine halves
        acc01.x += __shfl_xor(acc01.x, 32);
        acc01.y += __shfl_xor(acc01.y, 32);
        acc23.x += __shfl_xor(acc23.x, 32);
        acc23.y += __shfl_xor(acc23.y, 32);
        if (half == 0) {
            int p0 = li * 4;
            int f0 = ((p0 & 7) << 4) | (p0 >> 3);
            int f1 = (((p0 + 1) & 7) << 4) | ((p0 + 1) >> 3);
            int f2 = (((p0 + 2) & 7) << 4) | ((p0 + 2) >> 3);
            int f3 = (((p0 + 3) & 7) << 4) | ((p0 + 3) >> 3);
            f32x4 a;
            a[0] = fmaxf(fmaf(acc01.x, di, b1[f0]), 0.f);
            a[1] = fmaxf(fmaf(acc01.y, di, b1[f1]), 0.f);
            a[2] = fmaxf(fmaf(acc23.x, di, b1[f2]), 0.f);
            a[3] = fmaxf(fmaf(acc23.y, di, b1[f3]), 0.f);
            a_lds4[wave][li] = a;
        }
    }
    __syncthreads();
    if (d < N) {
        int c = lane & 15, kg = lane >> 4;
        const float* a_ldsf = (const float*)a_lds4[wave];
        const float* w2b = W2 + kg * 64 + c;
        float p = 0.f;
#pragma unroll
        for (int i = 0; i < 32; i++) {
            int w2off = ((i & 7) << 8) + ((i >> 3) << 4);
            p = fmaf(a_ldsf[kg * 32 + i], w2b[w2off], p);
        }
        p += __shfl_xor(p, 16);
        p += __shfl_xor(p, 32);
        if (lane < 16) H2[(size_t)d * NCLS + c] = f2bf(p * di);
    }
}

// ---------------- agg2 + log_softmax: 8 lanes/node, 2 classes/lane, 16-padded lists ----------------
__global__ __launch_bounds__(256, 8) void agg2_kernel(const unsigned short* __restrict__ H2,
                                                      const int* __restrict__ rowInfo,
                                                      const int* __restrict__ col,
                                                      const float* __restrict__ dinv,
                                                      const float* __restrict__ b2,
                                                      float* __restrict__ OUT, int N) {
    int tid = threadIdx.x;
    int g = tid >> 3, q = tid & 7;
    int d = blockIdx.x * 32 + g;
    if (d >= N) return;
    unsigned cb = (unsigned)q * 4;
    const char* H2b = (const char*)H2;
    float di = dinv[d];
    unsigned u = *(const unsigned*)(H2b + (((unsigned)d << 5) | cb));
    f32x2 acc; acc.x = bflo(u); acc.y = bfhi(u);
    int info = rowInfo[d];
    int jb = (info >> 12) << 4;
    int jend = jb + ((info & 0xFFF) << 4);
    for (int j = jb; j < jend; j += 8) {
        unsigned u0 = *(const unsigned*)(H2b + (((unsigned)col[j + 0] << 5) | cb));
        unsigned u1 = *(const unsigned*)(H2b + (((unsigned)col[j + 1] << 5) | cb));
        unsigned u2 = *(const unsigned*)(H2b + (((unsigned)col[j + 2] << 5) | cb));
        unsigned u3 = *(const unsigned*)(H2b + (((unsigned)col[j + 3] << 5) | cb));
        unsigned u4 = *(const unsigned*)(H2b + (((unsigned)col[j + 4] << 5) | cb));
        unsigned u5 = *(const unsigned*)(H2b + (((unsigned)col[j + 5] << 5) | cb));
        unsigned u6 = *(const unsigned*)(H2b + (((unsigned)col[j + 6] << 5) | cb));
        unsigned u7 = *(const unsigned*)(H2b + (((unsigned)col[j + 7] << 5) | cb));
        f32x2 v0; v0.x = bflo(u0); v0.y = bfhi(u0);
        f32x2 v1; v1.x = bflo(u1); v1.y = bfhi(u1);
        f32x2 v2; v2.x = bflo(u2); v2.y = bfhi(u2);
        f32x2 v3; v3.x = bflo(u3); v3.y = bfhi(u3);
        f32x2 v4; v4.x = bflo(u4); v4.y = bfhi(u4);
        f32x2 v5; v5.x = bflo(u5); v5.y = bfhi(u5);
        f32x2 v6; v6.x = bflo(u6); v6.y = bfhi(u6);
        f32x2 v7; v7.x = bflo(u7); v7.y = bfhi(u7);
        acc += ((v0 + v1) + (v2 + v3)) + ((v4 + v5) + (v6 + v7));
    }
    float l0 = fmaf(acc.x, di, b2[q * 2]);
    float l1 = fmaf(acc.y, di, b2[q * 2 + 1]);
    float m = fmaxf(l0, l1);
    m = fmaxf(m, __shfl_xor(m, 1, 8));
    m = fmaxf(m, __shfl_xor(m, 2, 8));
    m = fmaxf(m, __shfl_xor(m, 4, 8));
    float e = __expf(l0 - m) + __expf(l1 - m);
    e += __shfl_xor(e, 1, 8);
    e += __shfl_xor(e, 2, 8);
    e += __shfl_xor(e, 4, 8);
    float ls = __logf(e);
    float2 o; o.x = l0 - m - ls; o.y = l1 - m - ls;
    *(float2*)(OUT + ((size_t)d << 4) + q * 2) = o;
}

// ---------------- launch ----------------
extern "C" void kernel_launch(void* const* d_in, const int* in_sizes, int n_in,
                              void* d_out, int out_size, void* d_ws, size_t ws_size,
                              hipStream_t stream) {
    const float* x  = (const float*)d_in[0];
    const int*   ei = (const int*)d_in[1];
    const float* W1 = (const float*)d_in[2];
    const float* b1 = (const float*)d_in[3];
    const float* W2 = (const float*)d_in[4];
    const float* b2 = (const float*)d_in[5];
    float* out = (float*)d_out;

    const int N = in_sizes[0] / F_IN;    // 100000
    const int E = in_sizes[1] / 2;       // 1600000
    const int* src = ei;
    const int* dst = ei + E;
    const int nb = (N + (1 << BSH) - 1) >> BSH;   // 196 buckets

    // workspace layout (256B aligned)
    char* ws = (char*)d_ws;
    size_t off = 0;
    auto alloc = [&](size_t bytes) {
        size_t o = off;
        off += (bytes + 255) & ~(size_t)255;
        return (void*)(ws + o);
    };
    int*            bucketCur   = (int*)alloc(NBMAX * 4);
    int*            rowInfo     = (int*)alloc((size_t)N * 4);
    float*          dinv        = (float*)alloc((size_t)(N + 1) * 4);
    int*            colw        = (int*)alloc((size_t)NBMAX * PCAP * 4);
    unsigned short* w1f         = (unsigned short*)alloc(32768 * 2);
    unsigned short* h2          = (unsigned short*)alloc((size_t)(N + 1) * NCLS * 2);
    // pairs and h1 must NOT overlap (csr reads pairs while gemm writes h1 in same kernel)
    int2*           pairs       = (int2*)alloc((size_t)NBMAX * CAP * 8);
    unsigned char*  h1          = (unsigned char*)alloc((size_t)(N + 1) * DIM);
    (void)ws_size;

    const int gridE = (E + 8191) / 8192;   // 196

    init_kernel<<<128, 256, 0, stream>>>(W1, w1f, bucketCur,
                                         (unsigned*)(h1 + (size_t)N * DIM),
                                         (unsigned*)(h2 + (size_t)N * NCLS),
                                         dinv, N);
    part_kernel<<<gridE, 1024, 0, stream>>>(src, dst, bucketCur, pairs, E);
    csr_gemm_kernel<<<nb + (N + 63) / 64, 256, 0, stream>>>(pairs, bucketCur, rowInfo, dinv, colw,
                                                            x, w1f, h1, N, nb);
    agg1_kernel<<<(N + 3) / 4, 256, 0, stream>>>(h1, rowInfo, colw, dinv, b1, W2, h2, N);
    agg2_kernel<<<(N + 31) / 32, 256, 0, stream>>>(h2, rowInfo, colw, dinv, b2, out, N);
}

// Round 20
// 140.150 us; speedup vs baseline: 1.4792x; 1.0247x over previous
//
#include <hip/hip_runtime.h>
#include <hip/hip_bf16.h>

// ---------------- problem constants ----------------
#define F_IN   256
#define DIM    128
#define NCLS   16
#define BSH    9           // bucket shift: 512 nodes per bucket
#define NBMAX  256         // max buckets (N<=131072)
#define CAP    10240       // per-bucket pairs capacity (expected ~8.2K, +22 sigma)
#define PCAP   18432       // per-bucket padded col region (CAP + 16*512 pad headroom)

typedef short bf16x8 __attribute__((ext_vector_type(8)));
typedef float f32x4  __attribute__((ext_vector_type(4)));
typedef float f32x2  __attribute__((ext_vector_type(2)));

__device__ __forceinline__ unsigned short f2bf(float f) {
    union { float f; unsigned u; } v; v.f = f;
    unsigned r = v.u + 0x7fffu + ((v.u >> 16) & 1u);   // RNE
    return (unsigned short)(r >> 16);
}
__device__ __forceinline__ float bflo(unsigned v) { return __uint_as_float(v << 16); }
__device__ __forceinline__ float bfhi(unsigned v) { return __uint_as_float(v & 0xffff0000u); }

// ---------------- init: bucket cursors + W1 repack + dummy rows + dinv[N]=0 ----------------
__global__ void init_kernel(const float* __restrict__ W1, unsigned short* __restrict__ W1f,
                            int* __restrict__ bucketCur,
                            unsigned* __restrict__ h1dummy, unsigned* __restrict__ h2dummy,
                            float* __restrict__ dinv, int N) {
    int t = blockIdx.x * blockDim.x + threadIdx.x;
    if (blockIdx.x == 0) {
        bucketCur[threadIdx.x] = threadIdx.x * CAP;               // NBMAX = 256 = blockDim
        if (threadIdx.x < 32) h1dummy[threadIdx.x] = 0;           // 128 B fp8 dummy row
        else if (threadIdx.x < 40) h2dummy[threadIdx.x - 32] = 0; // 32 B bf16 dummy row
        else if (threadIdx.x == 40) dinv[N] = 0.f;                // dummy dinv -> pad edges = 0
    }
    if (t >= 8 * 32 * 16 * 8) return;
    int j = t & 7, c = (t >> 3) & 15, g = (t >> 7) & 31, f = t >> 12;
    W1f[t] = f2bf(W1[(g * 8 + j) * DIM + f * 16 + c]);
}

// ---------------- part: partition edges into per-bucket capacity regions ----------------
__global__ __launch_bounds__(1024) void part_kernel(const int* __restrict__ src,
                                                    const int* __restrict__ dst,
                                                    int* __restrict__ bucketCur,
                                                    int2* __restrict__ pairs, int E) {
    __shared__ int hist[NBMAX];
    __shared__ int pos[NBMAX];
    int t = threadIdx.x;
    int base = blockIdx.x * 8192;
    int s[8], d[8];
#pragma unroll
    for (int k = 0; k < 8; k++) {
        int i = base + k * 1024 + t;
        bool v = (i < E);
        s[k] = v ? src[i] : 0;
        d[k] = v ? dst[i] : -1;
    }
    if (t < NBMAX) hist[t] = 0;
    __syncthreads();
#pragma unroll
    for (int k = 0; k < 8; k++)
        if (d[k] >= 0) atomicAdd(&hist[d[k] >> BSH], 1);
    __syncthreads();
    if (t < NBMAX && hist[t]) pos[t] = atomicAdd(&bucketCur[t], hist[t]);
    __syncthreads();
#pragma unroll
    for (int k = 0; k < 8; k++)
        if (d[k] >= 0) {
            int p = atomicAdd(&pos[d[k] >> BSH], 1);
            pairs[p] = make_int2(s[k], d[k]);
        }
}

// ---------------- fat kernel: csr (blocks 0..nbCsr-1) || gemm1 (rest) ----------------
// csr: per-node counts, 16-padded local scan -> rowInfo/dinv, LDS-cursor scatter -> col.
// gemm: H1u = fp8(X @ W1) UNSCALED; ALL 16 X-loads issued up front (one latency exposure).
__global__ __launch_bounds__(256) void csr_gemm_kernel(
        const int2* __restrict__ pairs, const int* __restrict__ bucketCur,
        int* __restrict__ rowInfo, float* __restrict__ dinv, int* __restrict__ col,
        const float* __restrict__ X, const unsigned short* __restrict__ W1f,
        unsigned char* __restrict__ H1, int N, int nbCsr) {
    __shared__ int cnt[512];
    __shared__ int part[256];
    int t = threadIdx.x;

    if (blockIdx.x < nbCsr) {
        // ---- CSR body ----
        int b = blockIdx.x;
        int n0 = b << BSH;
        int nn = N - n0; if (nn > 512) nn = 512;
        int in0 = b * CAP;
        int inEnd = bucketCur[b];
        int out0 = b * PCAP;

        cnt[t] = 0; cnt[t + 256] = 0;
        __syncthreads();
        for (int p = in0 + t; p < inEnd; p += 256)
            atomicAdd(&cnt[pairs[p].y - n0], 1);
        __syncthreads();

        int i0 = t * 2;
        int c0 = cnt[i0], c1 = cnt[i0 + 1];
        int p0 = (c0 + 15) & ~15, p1 = (c1 + 15) & ~15;   // pad to 16
        int tsum = p0 + p1;
        part[t] = tsum;
        __syncthreads();
        for (int off = 1; off < 256; off <<= 1) {
            int u = (t >= off) ? part[t - off] : 0;
            __syncthreads();
            part[t] += u;
            __syncthreads();
        }
        int run = out0 + part[t] - tsum;
        int e0 = run, e1 = e0 + p0;
        __syncthreads();
        // rowInfo = (start>>4)<<12 | nchunks16
        if (i0 + 0 < nn) { rowInfo[n0 + i0 + 0] = ((e0 >> 4) << 12) | (p0 >> 4); dinv[n0 + i0 + 0] = rsqrtf((float)(c0 + 1)); }
        if (i0 + 1 < nn) { rowInfo[n0 + i0 + 1] = ((e1 >> 4) << 12) | (p1 >> 4); dinv[n0 + i0 + 1] = rsqrtf((float)(c1 + 1)); }
        cnt[i0] = e0; cnt[i0 + 1] = e1;    // cursors
        __syncthreads();

        for (int p = in0 + t; p < inEnd; p += 256) {
            int2 e = pairs[p];
            int q = atomicAdd(&cnt[e.y - n0], 1);
            col[q] = e.x;
        }
        __syncthreads();
        if (i0 + 0 < nn) for (int q = c0; q < p0; q++) col[e0 + q] = N;   // dummy pad
        if (i0 + 1 < nn) for (int q = c1; q < p1; q++) col[e1 + q] = N;
    } else {
        // ---- GEMM body: 16 rows/wave, 64 rows/block; full X preload ----
        int gb = blockIdx.x - nbCsr;
        int wm = t >> 6, l = t & 63;
        int lr = l & 15, lg = l >> 4;
        int bm = gb * 64 + wm * 16;

        int r = bm + lr;
        r = (r < N) ? r : (N - 1);
        const float* xp = X + (size_t)r * F_IN + lg * 8;

        // issue all 16 X loads up front: one latency exposure instead of eight
        float4 u[16];
#pragma unroll
        for (int s = 0; s < 8; s++) {
            u[2 * s + 0] = *(const float4*)(xp + s * 32);
            u[2 * s + 1] = *(const float4*)(xp + s * 32 + 4);
        }

        f32x4 acc[8];
#pragma unroll
        for (int f = 0; f < 8; f++) acc[f] = (f32x4){0.f, 0.f, 0.f, 0.f};

#pragma unroll
        for (int s = 0; s < 8; s++) {            // k-step of 32, all data in registers
            float4 u0 = u[2 * s + 0];
            float4 u1 = u[2 * s + 1];
            bf16x8 a;
            a[0] = (short)f2bf(u0.x); a[1] = (short)f2bf(u0.y);
            a[2] = (short)f2bf(u0.z); a[3] = (short)f2bf(u0.w);
            a[4] = (short)f2bf(u1.x); a[5] = (short)f2bf(u1.y);
            a[6] = (short)f2bf(u1.z); a[7] = (short)f2bf(u1.w);
#pragma unroll
            for (int f = 0; f < 8; f++) {
                const unsigned short* bp = W1f + ((((f * 32 + s * 4 + lg) * 16) + lr) << 3);
                bf16x8 b = *(const bf16x8*)bp;
                acc[f] = __builtin_amdgcn_mfma_f32_16x16x32_bf16(a, b, acc[f], 0, 0, 0);
            }
        }
#pragma unroll
        for (int rr = 0; rr < 4; rr++) {
            int row = bm + lg * 4 + rr;
            if (row < N) {
                int w0 = __builtin_amdgcn_cvt_pk_fp8_f32(acc[0][rr], acc[1][rr], 0, false);
                w0 = __builtin_amdgcn_cvt_pk_fp8_f32(acc[2][rr], acc[3][rr], w0, true);
                int w1 = __builtin_amdgcn_cvt_pk_fp8_f32(acc[4][rr], acc[5][rr], 0, false);
                w1 = __builtin_amdgcn_cvt_pk_fp8_f32(acc[6][rr], acc[7][rr], w1, true);
                uint2 pk; pk.x = (unsigned)w0; pk.y = (unsigned)w1;
                *(uint2*)(H1 + ((size_t)row << 7) + lr * 8) = pk;
            }
        }
    }
}

// ---------------- agg1 fused: sum(dv_s * H1u[s]) -> *di + b1 -> relu -> @W2 -> *di -> H2(bf16) ----------------
// one wave per dst node; lanes 0-31 edge A's row (dword = 4 fp8), lanes 32-63 edge B's row.
// Rows 16-padded with dummy node N (dinv[N]=0 -> pad contributes 0). 8 pair-gathers in flight.
__global__ __launch_bounds__(256, 8) void agg1_kernel(const unsigned char* __restrict__ H1,
                                                      const int* __restrict__ rowInfo,
                                                      const int* __restrict__ col,
                                                      const float* __restrict__ dinv,
                                                      const float* __restrict__ b1,
                                                      const float* __restrict__ W2,
                                                      unsigned short* __restrict__ H2, int N) {
    __shared__ f32x4 a_lds4[4][32];
    int tid = threadIdx.x;
    int wave = tid >> 6, lane = tid & 63;
    int d = blockIdx.x * 4 + wave;
    int half = lane >> 5;
    int li = lane & 31;
    unsigned kb4 = (unsigned)li * 4;

    float di = 0.f;
    if (d < N) {
        di = dinv[d];
        unsigned sg = *(const unsigned*)(H1 + (((unsigned)d << 7) | kb4));   // self row (unscaled)
        if (half) sg = 0u;
        f32x2 s0v = __builtin_amdgcn_cvt_pk_f32_fp8((int)sg, false);
        f32x2 s1v = __builtin_amdgcn_cvt_pk_f32_fp8((int)sg, true);
        f32x2 acc01, acc23;
        acc01.x = s0v.x * di; acc01.y = s0v.y * di;
        acc23.x = s1v.x * di; acc23.y = s1v.y * di;

        int info = rowInfo[d];
        int jb = (info >> 12) << 4;
        int jend = jb + ((info & 0xFFF) << 4);
        for (int j0 = jb; j0 < jend; j0 += 64) {
            int cnt = jend - j0; if (cnt > 64) cnt = 64;   // multiple of 16
            int eidx = col[j0 + lane];         // 64 edges: one VMEM
            // clamp: tail lanes may read uninitialized (poison) col at bucket tails
            if ((unsigned)eidx > (unsigned)N) eidx = N;
            float dv = dinv[eidx];             // 64 dinv: one VMEM gather (dinv[N]=0)
            for (int kk = 0; kk < cnt; kk += 16) {         // 8 pair-gathers in flight
                int sA = __shfl(eidx, kk + 0 + half),  sB = __shfl(eidx, kk + 2 + half);
                int sC = __shfl(eidx, kk + 4 + half),  sD = __shfl(eidx, kk + 6 + half);
                int sE = __shfl(eidx, kk + 8 + half),  sF = __shfl(eidx, kk + 10 + half);
                int sG = __shfl(eidx, kk + 12 + half), sH = __shfl(eidx, kk + 14 + half);
                float vA = __shfl(dv, kk + 0 + half),  vB = __shfl(dv, kk + 2 + half);
                float vC = __shfl(dv, kk + 4 + half),  vD = __shfl(dv, kk + 6 + half);
                float vE = __shfl(dv, kk + 8 + half),  vF = __shfl(dv, kk + 10 + half);
                float vG = __shfl(dv, kk + 12 + half), vH = __shfl(dv, kk + 14 + half);
                unsigned gA = *(const unsigned*)(H1 + (((unsigned)sA << 7) | kb4));
                unsigned gB = *(const unsigned*)(H1 + (((unsigned)sB << 7) | kb4));
                unsigned gC = *(const unsigned*)(H1 + (((unsigned)sC << 7) | kb4));
                unsigned gD = *(const unsigned*)(H1 + (((unsigned)sD << 7) | kb4));
                unsigned gE = *(const unsigned*)(H1 + (((unsigned)sE << 7) | kb4));
                unsigned gF = *(const unsigned*)(H1 + (((unsigned)sF << 7) | kb4));
                unsigned gG = *(const unsigned*)(H1 + (((unsigned)sG << 7) | kb4));
                unsigned gH = *(const unsigned*)(H1 + (((unsigned)sH << 7) | kb4));
                f32x2 t0, t1;
                t0 = __builtin_amdgcn_cvt_pk_f32_fp8((int)gA, false);
                t1 = __builtin_amdgcn_cvt_pk_f32_fp8((int)gA, true);
                acc01.x = fmaf(t0.x, vA, acc01.x); acc01.y = fmaf(t0.y, vA, acc01.y);
                acc23.x = fmaf(t1.x, vA, acc23.x); acc23.y = fmaf(t1.y, vA, acc23.y);
                t0 = __builtin_amdgcn_cvt_pk_f32_fp8((int)gB, false);
                t1 = __builtin_amdgcn_cvt_pk_f32_fp8((int)gB, true);
                acc01.x = fmaf(t0.x, vB, acc01.x); acc01.y = fmaf(t0.y, vB, acc01.y);
                acc23.x = fmaf(t1.x, vB, acc23.x); acc23.y = fmaf(t1.y, vB, acc23.y);
                t0 = __builtin_amdgcn_cvt_pk_f32_fp8((int)gC, false);
                t1 = __builtin_amdgcn_cvt_pk_f32_fp8((int)gC, true);
                acc01.x = fmaf(t0.x, vC, acc01.x); acc01.y = fmaf(t0.y, vC, acc01.y);
                acc23.x = fmaf(t1.x, vC, acc23.x); acc23.y = fmaf(t1.y, vC, acc23.y);
                t0 = __builtin_amdgcn_cvt_pk_f32_fp8((int)gD, false);
                t1 = __builtin_amdgcn_cvt_pk_f32_fp8((int)gD, true);
                acc01.x = fmaf(t0.x, vD, acc01.x); acc01.y = fmaf(t0.y, vD, acc01.y);
                acc23.x = fmaf(t1.x, vD, acc23.x); acc23.y = fmaf(t1.y, vD, acc23.y);
                t0 = __builtin_amdgcn_cvt_pk_f32_fp8((int)gE, false);
                t1 = __builtin_amdgcn_cvt_pk_f32_fp8((int)gE, true);
                acc01.x = fmaf(t0.x, vE, acc01.x); acc01.y = fmaf(t0.y, vE, acc01.y);
                acc23.x = fmaf(t1.x, vE, acc23.x); acc23.y = fmaf(t1.y, vE, acc23.y);
                t0 = __builtin_amdgcn_cvt_pk_f32_fp8((int)gF, false);
                t1 = __builtin_amdgcn_cvt_pk_f32_fp8((int)gF, true);
                acc01.x = fmaf(t0.x, vF, acc01.x); acc01.y = fmaf(t0.y, vF, acc01.y);
                acc23.x = fmaf(t1.x, vF, acc23.x); acc23.y = fmaf(t1.y, vF, acc23.y);
                t0 = __builtin_amdgcn_cvt_pk_f32_fp8((int)gG, false);
                t1 = __builtin_amdgcn_cvt_pk_f32_fp8((int)gG, true);
                acc01.x = fmaf(t0.x, vG, acc01.x); acc01.y = fmaf(t0.y, vG, acc01.y);
                acc23.x = fmaf(t1.x, vG, acc23.x); acc23.y = fmaf(t1.y, vG, acc23.y);
                t0 = __builtin_amdgcn_cvt_pk_f32_fp8((int)gH, false);
                t1 = __builtin_amdgcn_cvt_pk_f32_fp8((int)gH, true);
                acc01.x = fmaf(t0.x, vH, acc01.x); acc01.y = fmaf(t0.y, vH, acc01.y);
                acc23.x = fmaf(t1.x, vH, acc23.x); acc23.y = fmaf(t1.y, vH, acc23.y);
            }
        }
        // combine halves
        acc01.x += __shfl_xor(acc01.x, 32);
        acc01.y += __shfl_xor(acc01.y, 32);
        acc23.x += __shfl_xor(acc23.x, 32);
        acc23.y += __shfl_xor(acc23.y, 32);
        if (half == 0) {
            int p0 = li * 4;
            int f0 = ((p0 & 7) << 4) | (p0 >> 3);
            int f1 = (((p0 + 1) & 7) << 4) | ((p0 + 1) >> 3);
            int f2 = (((p0 + 2) & 7) << 4) | ((p0 + 2) >> 3);
            int f3 = (((p0 + 3) & 7) << 4) | ((p0 + 3) >> 3);
            f32x4 a;
            a[0] = fmaxf(fmaf(acc01.x, di, b1[f0]), 0.f);
            a[1] = fmaxf(fmaf(acc01.y, di, b1[f1]), 0.f);
            a[2] = fmaxf(fmaf(acc23.x, di, b1[f2]), 0.f);
            a[3] = fmaxf(fmaf(acc23.y, di, b1[f3]), 0.f);
            a_lds4[wave][li] = a;
        }
    }
    __syncthreads();
    if (d < N) {
        int c = lane & 15, kg = lane >> 4;
        const float* a_ldsf = (const float*)a_lds4[wave];
        const float* w2b = W2 + kg * 64 + c;
        float p = 0.f;
#pragma unroll
        for (int i = 0; i < 32; i++) {
            int w2off = ((i & 7) << 8) + ((i >> 3) << 4);
            p = fmaf(a_ldsf[kg * 32 + i], w2b[w2off], p);
        }
        p += __shfl_xor(p, 16);
        p += __shfl_xor(p, 32);
        if (lane < 16) H2[(size_t)d * NCLS + c] = f2bf(p * di);
    }
}

// ---------------- agg2 + log_softmax: 8 lanes/node, 2 classes/lane, 16-padded lists ----------------
__global__ __launch_bounds__(256, 8) void agg2_kernel(const unsigned short* __restrict__ H2,
                                                      const int* __restrict__ rowInfo,
                                                      const int* __restrict__ col,
                                                      const float* __restrict__ dinv,
                                                      const float* __restrict__ b2,
                                                      float* __restrict__ OUT, int N) {
    int tid = threadIdx.x;
    int g = tid >> 3, q = tid & 7;
    int d = blockIdx.x * 32 + g;
    if (d >= N) return;
    unsigned cb = (unsigned)q * 4;
    const char* H2b = (const char*)H2;
    float di = dinv[d];
    unsigned u = *(const unsigned*)(H2b + (((unsigned)d << 5) | cb));
    f32x2 acc; acc.x = bflo(u); acc.y = bfhi(u);
    int info = rowInfo[d];
    int jb = (info >> 12) << 4;
    int jend = jb + ((info & 0xFFF) << 4);
    for (int j = jb; j < jend; j += 8) {
        unsigned u0 = *(const unsigned*)(H2b + (((unsigned)col[j + 0] << 5) | cb));
        unsigned u1 = *(const unsigned*)(H2b + (((unsigned)col[j + 1] << 5) | cb));
        unsigned u2 = *(const unsigned*)(H2b + (((unsigned)col[j + 2] << 5) | cb));
        unsigned u3 = *(const unsigned*)(H2b + (((unsigned)col[j + 3] << 5) | cb));
        unsigned u4 = *(const unsigned*)(H2b + (((unsigned)col[j + 4] << 5) | cb));
        unsigned u5 = *(const unsigned*)(H2b + (((unsigned)col[j + 5] << 5) | cb));
        unsigned u6 = *(const unsigned*)(H2b + (((unsigned)col[j + 6] << 5) | cb));
        unsigned u7 = *(const unsigned*)(H2b + (((unsigned)col[j + 7] << 5) | cb));
        f32x2 v0; v0.x = bflo(u0); v0.y = bfhi(u0);
        f32x2 v1; v1.x = bflo(u1); v1.y = bfhi(u1);
        f32x2 v2; v2.x = bflo(u2); v2.y = bfhi(u2);
        f32x2 v3; v3.x = bflo(u3); v3.y = bfhi(u3);
        f32x2 v4; v4.x = bflo(u4); v4.y = bfhi(u4);
        f32x2 v5; v5.x = bflo(u5); v5.y = bfhi(u5);
        f32x2 v6; v6.x = bflo(u6); v6.y = bfhi(u6);
        f32x2 v7; v7.x = bflo(u7); v7.y = bfhi(u7);
        acc += ((v0 + v1) + (v2 + v3)) + ((v4 + v5) + (v6 + v7));
    }
    float l0 = fmaf(acc.x, di, b2[q * 2]);
    float l1 = fmaf(acc.y, di, b2[q * 2 + 1]);
    float m = fmaxf(l0, l1);
    m = fmaxf(m, __shfl_xor(m, 1, 8));
    m = fmaxf(m, __shfl_xor(m, 2, 8));
    m = fmaxf(m, __shfl_xor(m, 4, 8));
    float e = __expf(l0 - m) + __expf(l1 - m);
    e += __shfl_xor(e, 1, 8);
    e += __shfl_xor(e, 2, 8);
    e += __shfl_xor(e, 4, 8);
    float ls = __logf(e);
    float2 o; o.x = l0 - m - ls; o.y = l1 - m - ls;
    *(float2*)(OUT + ((size_t)d << 4) + q * 2) = o;
}

// ---------------- launch ----------------
extern "C" void kernel_launch(void* const* d_in, const int* in_sizes, int n_in,
                              void* d_out, int out_size, void* d_ws, size_t ws_size,
                              hipStream_t stream) {
    const float* x  = (const float*)d_in[0];
    const int*   ei = (const int*)d_in[1];
    const float* W1 = (const float*)d_in[2];
    const float* b1 = (const float*)d_in[3];
    const float* W2 = (const float*)d_in[4];
    const float* b2 = (const float*)d_in[5];
    float* out = (float*)d_out;

    const int N = in_sizes[0] / F_IN;    // 100000
    const int E = in_sizes[1] / 2;       // 1600000
    const int* src = ei;
    const int* dst = ei + E;
    const int nb = (N + (1 << BSH) - 1) >> BSH;   // 196 buckets

    // workspace layout (256B aligned)
    char* ws = (char*)d_ws;
    size_t off = 0;
    auto alloc = [&](size_t bytes) {
        size_t o = off;
        off += (bytes + 255) & ~(size_t)255;
        return (void*)(ws + o);
    };
    int*            bucketCur   = (int*)alloc(NBMAX * 4);
    int*            rowInfo     = (int*)alloc((size_t)N * 4);
    float*          dinv        = (float*)alloc((size_t)(N + 1) * 4);
    int*            colw        = (int*)alloc((size_t)NBMAX * PCAP * 4);
    unsigned short* w1f         = (unsigned short*)alloc(32768 * 2);
    unsigned short* h2          = (unsigned short*)alloc((size_t)(N + 1) * NCLS * 2);
    // pairs and h1 must NOT overlap (csr reads pairs while gemm writes h1 in same kernel)
    int2*           pairs       = (int2*)alloc((size_t)NBMAX * CAP * 8);
    unsigned char*  h1          = (unsigned char*)alloc((size_t)(N + 1) * DIM);
    (void)ws_size;

    const int gridE = (E + 8191) / 8192;   // 196

    init_kernel<<<128, 256, 0, stream>>>(W1, w1f, bucketCur,
                                         (unsigned*)(h1 + (size_t)N * DIM),
                                         (unsigned*)(h2 + (size_t)N * NCLS),
                                         dinv, N);
    part_kernel<<<gridE, 1024, 0, stream>>>(src, dst, bucketCur, pairs, E);
    csr_gemm_kernel<<<nb + (N + 63) / 64, 256, 0, stream>>>(pairs, bucketCur, rowInfo, dinv, colw,
                                                            x, w1f, h1, N, nb);
    agg1_kernel<<<(N + 3) / 4, 256, 0, stream>>>(h1, rowInfo, colw, dinv, b1, W2, h2, N);
    agg2_kernel<<<(N + 31) / 32, 256, 0, stream>>>(h2, rowInfo, colw, dinv, b2, out, N);
}

// Round 22
// 139.277 us; speedup vs baseline: 1.4884x; 1.0063x over previous
//
#include <hip/hip_runtime.h>
#include <hip/hip_bf16.h>

// ---------------- problem constants ----------------
#define F_IN   256
#define DIM    128
#define NCLS   16
#define BSH    9           // bucket shift: 512 nodes per bucket
#define NBMAX  256         // max buckets (N<=131072)
#define CAP    10240       // per-bucket pairs capacity (expected ~8.2K, +22 sigma)
#define PCAP   18432       // per-bucket padded col region (CAP + 16*512 pad headroom)

typedef short bf16x8 __attribute__((ext_vector_type(8)));
typedef float f32x4  __attribute__((ext_vector_type(4)));
typedef float f32x2  __attribute__((ext_vector_type(2)));

__device__ __forceinline__ unsigned short f2bf(float f) {
    union { float f; unsigned u; } v; v.f = f;
    unsigned r = v.u + 0x7fffu + ((v.u >> 16) & 1u);   // RNE
    return (unsigned short)(r >> 16);
}
__device__ __forceinline__ float bflo(unsigned v) { return __uint_as_float(v << 16); }
__device__ __forceinline__ float bfhi(unsigned v) { return __uint_as_float(v & 0xffff0000u); }

// ---------------- init: bucket cursors + W1 repack + dummy rows + dinv[N]=0 ----------------
__global__ void init_kernel(const float* __restrict__ W1, unsigned short* __restrict__ W1f,
                            int* __restrict__ bucketCur,
                            unsigned* __restrict__ h1dummy, unsigned* __restrict__ h2dummy,
                            float* __restrict__ dinv, int N) {
    int t = blockIdx.x * blockDim.x + threadIdx.x;
    if (blockIdx.x == 0) {
        bucketCur[threadIdx.x] = threadIdx.x * CAP;               // NBMAX = 256 = blockDim
        if (threadIdx.x < 32) h1dummy[threadIdx.x] = 0;           // 128 B fp8 dummy row
        else if (threadIdx.x < 40) h2dummy[threadIdx.x - 32] = 0; // 32 B bf16 dummy row
        else if (threadIdx.x == 40) dinv[N] = 0.f;                // dummy dinv -> pad edges = 0
    }
    if (t >= 8 * 32 * 16 * 8) return;
    int j = t & 7, c = (t >> 3) & 15, g = (t >> 7) & 31, f = t >> 12;
    W1f[t] = f2bf(W1[(g * 8 + j) * DIM + f * 16 + c]);
}

// ---------------- part: partition edges into per-bucket capacity regions ----------------
__global__ __launch_bounds__(1024) void part_kernel(const int* __restrict__ src,
                                                    const int* __restrict__ dst,
                                                    int* __restrict__ bucketCur,
                                                    int2* __restrict__ pairs, int E) {
    __shared__ int hist[NBMAX];
    __shared__ int pos[NBMAX];
    int t = threadIdx.x;
    int base = blockIdx.x * 8192;
    int s[8], d[8];
#pragma unroll
    for (int k = 0; k < 8; k++) {
        int i = base + k * 1024 + t;
        bool v = (i < E);
        s[k] = v ? src[i] : 0;
        d[k] = v ? dst[i] : -1;
    }
    if (t < NBMAX) hist[t] = 0;
    __syncthreads();
#pragma unroll
    for (int k = 0; k < 8; k++)
        if (d[k] >= 0) atomicAdd(&hist[d[k] >> BSH], 1);
    __syncthreads();
    if (t < NBMAX && hist[t]) pos[t] = atomicAdd(&bucketCur[t], hist[t]);
    __syncthreads();
#pragma unroll
    for (int k = 0; k < 8; k++)
        if (d[k] >= 0) {
            int p = atomicAdd(&pos[d[k] >> BSH], 1);
            pairs[p] = make_int2(s[k], d[k]);
        }
}

// ---------------- fat kernel: csr (blocks 0..nbCsr-1) || gemm1 (rest) ----------------
// csr: per-node counts, 16-padded local scan -> rowInfo/dinv, LDS-cursor scatter -> col.
// gemm: H1u = fp8(X @ W1) UNSCALED; W1f staged in LDS (VMEM 80->16 per wave);
//       X preloaded before the staging barrier (one latency exposure, hidden by the copy).
__global__ __launch_bounds__(256) void csr_gemm_kernel(
        const int2* __restrict__ pairs, const int* __restrict__ bucketCur,
        int* __restrict__ rowInfo, float* __restrict__ dinv, int* __restrict__ col,
        const float* __restrict__ X, const unsigned short* __restrict__ W1f,
        unsigned char* __restrict__ H1, int N, int nbCsr) {
    __shared__ int sh[16384];   // 64KB: csr uses first 3KB; gemm uses all (W1f copy)
    int t = threadIdx.x;

    if (blockIdx.x < nbCsr) {
        // ---- CSR body ----
        int* cnt  = sh;
        int* part = sh + 512;
        int b = blockIdx.x;
        int n0 = b << BSH;
        int nn = N - n0; if (nn > 512) nn = 512;
        int in0 = b * CAP;
        int inEnd = bucketCur[b];
        int out0 = b * PCAP;

        cnt[t] = 0; cnt[t + 256] = 0;
        __syncthreads();
        for (int p = in0 + t; p < inEnd; p += 256)
            atomicAdd(&cnt[pairs[p].y - n0], 1);
        __syncthreads();

        int i0 = t * 2;
        int c0 = cnt[i0], c1 = cnt[i0 + 1];
        int p0 = (c0 + 15) & ~15, p1 = (c1 + 15) & ~15;   // pad to 16
        int tsum = p0 + p1;
        part[t] = tsum;
        __syncthreads();
        for (int off = 1; off < 256; off <<= 1) {
            int u = (t >= off) ? part[t - off] : 0;
            __syncthreads();
            part[t] += u;
            __syncthreads();
        }
        int run = out0 + part[t] - tsum;
        int e0 = run, e1 = e0 + p0;
        __syncthreads();
        // rowInfo = (start>>4)<<12 | nchunks16
        if (i0 + 0 < nn) { rowInfo[n0 + i0 + 0] = ((e0 >> 4) << 12) | (p0 >> 4); dinv[n0 + i0 + 0] = rsqrtf((float)(c0 + 1)); }
        if (i0 + 1 < nn) { rowInfo[n0 + i0 + 1] = ((e1 >> 4) << 12) | (p1 >> 4); dinv[n0 + i0 + 1] = rsqrtf((float)(c1 + 1)); }
        cnt[i0] = e0; cnt[i0 + 1] = e1;    // cursors
        __syncthreads();

        for (int p = in0 + t; p < inEnd; p += 256) {
            int2 e = pairs[p];
            int q = atomicAdd(&cnt[e.y - n0], 1);
            col[q] = e.x;
        }
        __syncthreads();
        if (i0 + 0 < nn) for (int q = c0; q < p0; q++) col[e0 + q] = N;   // dummy pad
        if (i0 + 1 < nn) for (int q = c1; q < p1; q++) col[e1 + q] = N;
    } else {
        // ---- GEMM body: 16 rows/wave, 64 rows/block ----
        int gb = blockIdx.x - nbCsr;
        int wm = t >> 6, l = t & 63;
        int lr = l & 15, lg = l >> 4;
        int bm = gb * 64 + wm * 16;

        int r = bm + lr;
        r = (r < N) ? r : (N - 1);
        const float* xp = X + (size_t)r * F_IN + lg * 8;

        // issue all 16 X loads BEFORE the staging barrier (barrier drains vmcnt ->
        // loads land under the W1f copy; compiler cannot sink them past it)
        float4 u[16];
#pragma unroll
        for (int s = 0; s < 8; s++) {
            u[2 * s + 0] = *(const float4*)(xp + s * 32);
            u[2 * s + 1] = *(const float4*)(xp + s * 32 + 4);
        }

        // stage entire repacked W1f (64KB) into LDS: 16 x uint4 per thread
        uint4* wv = (uint4*)sh;
        const uint4* wg = (const uint4*)W1f;
#pragma unroll
        for (int i = 0; i < 16; i++) wv[t + i * 256] = wg[t + i * 256];
        __syncthreads();
        const unsigned short* w1s = (const unsigned short*)sh;

        f32x4 acc[8];
#pragma unroll
        for (int f = 0; f < 8; f++) acc[f] = (f32x4){0.f, 0.f, 0.f, 0.f};

#pragma unroll
        for (int s = 0; s < 8; s++) {            // k-step of 32, X in regs, W1f in LDS
            float4 u0 = u[2 * s + 0];
            float4 u1 = u[2 * s + 1];
            bf16x8 a;
            a[0] = (short)f2bf(u0.x); a[1] = (short)f2bf(u0.y);
            a[2] = (short)f2bf(u0.z); a[3] = (short)f2bf(u0.w);
            a[4] = (short)f2bf(u1.x); a[5] = (short)f2bf(u1.y);
            a[6] = (short)f2bf(u1.z); a[7] = (short)f2bf(u1.w);
#pragma unroll
            for (int f = 0; f < 8; f++) {
                bf16x8 b = *(const bf16x8*)(w1s + ((((f * 32 + s * 4 + lg) * 16) + lr) << 3));
                acc[f] = __builtin_amdgcn_mfma_f32_16x16x32_bf16(a, b, acc[f], 0, 0, 0);
            }
        }
#pragma unroll
        for (int rr = 0; rr < 4; rr++) {
            int row = bm + lg * 4 + rr;
            if (row < N) {
                int w0 = __builtin_amdgcn_cvt_pk_fp8_f32(acc[0][rr], acc[1][rr], 0, false);
                w0 = __builtin_amdgcn_cvt_pk_fp8_f32(acc[2][rr], acc[3][rr], w0, true);
                int w1 = __builtin_amdgcn_cvt_pk_fp8_f32(acc[4][rr], acc[5][rr], 0, false);
                w1 = __builtin_amdgcn_cvt_pk_fp8_f32(acc[6][rr], acc[7][rr], w1, true);
                uint2 pk; pk.x = (unsigned)w0; pk.y = (unsigned)w1;
                *(uint2*)(H1 + ((size_t)row << 7) + lr * 8) = pk;
            }
        }
    }
}

// ---------------- agg1 fused: sum(dv_s * H1u[s]) -> *di + b1 -> relu -> @W2 -> *di -> H2(bf16) ----------------
// one wave per dst node; lanes 0-31 edge A's row (dword = 4 fp8), lanes 32-63 edge B's row.
// Rows 16-padded with dummy node N (dinv[N]=0 -> pad contributes 0). 8 pair-gathers in flight.
__global__ __launch_bounds__(256, 8) void agg1_kernel(const unsigned char* __restrict__ H1,
                                                      const int* __restrict__ rowInfo,
                                                      const int* __restrict__ col,
                                                      const float* __restrict__ dinv,
                                                      const float* __restrict__ b1,
                                                      const float* __restrict__ W2,
                                                      unsigned short* __restrict__ H2, int N) {
    __shared__ f32x4 a_lds4[4][32];
    int tid = threadIdx.x;
    int wave = tid >> 6, lane = tid & 63;
    int d = blockIdx.x * 4 + wave;
    int half = lane >> 5;
    int li = lane & 31;
    unsigned kb4 = (unsigned)li * 4;

    float di = 0.f;
    if (d < N) {
        di = dinv[d];
        unsigned sg = *(const unsigned*)(H1 + (((unsigned)d << 7) | kb4));   // self row (unscaled)
        if (half) sg = 0u;
        f32x2 s0v = __builtin_amdgcn_cvt_pk_f32_fp8((int)sg, false);
        f32x2 s1v = __builtin_amdgcn_cvt_pk_f32_fp8((int)sg, true);
        f32x2 acc01, acc23;
        acc01.x = s0v.x * di; acc01.y = s0v.y * di;
        acc23.x = s1v.x * di; acc23.y = s1v.y * di;

        int info = rowInfo[d];
        int jb = (info >> 12) << 4;
        int jend = jb + ((info & 0xFFF) << 4);
        for (int j0 = jb; j0 < jend; j0 += 64) {
            int cnt = jend - j0; if (cnt > 64) cnt = 64;   // multiple of 16
            int eidx = col[j0 + lane];         // 64 edges: one VMEM
            // clamp: tail lanes may read uninitialized (poison) col at bucket tails
            if ((unsigned)eidx > (unsigned)N) eidx = N;
            float dv = dinv[eidx];             // 64 dinv: one VMEM gather (dinv[N]=0)
            for (int kk = 0; kk < cnt; kk += 16) {         // 8 pair-gathers in flight
                int sA = __shfl(eidx, kk + 0 + half),  sB = __shfl(eidx, kk + 2 + half);
                int sC = __shfl(eidx, kk + 4 + half),  sD = __shfl(eidx, kk + 6 + half);
                int sE = __shfl(eidx, kk + 8 + half),  sF = __shfl(eidx, kk + 10 + half);
                int sG = __shfl(eidx, kk + 12 + half), sH = __shfl(eidx, kk + 14 + half);
                float vA = __shfl(dv, kk + 0 + half),  vB = __shfl(dv, kk + 2 + half);
                float vC = __shfl(dv, kk + 4 + half),  vD = __shfl(dv, kk + 6 + half);
                float vE = __shfl(dv, kk + 8 + half),  vF = __shfl(dv, kk + 10 + half);
                float vG = __shfl(dv, kk + 12 + half), vH = __shfl(dv, kk + 14 + half);
                unsigned gA = *(const unsigned*)(H1 + (((unsigned)sA << 7) | kb4));
                unsigned gB = *(const unsigned*)(H1 + (((unsigned)sB << 7) | kb4));
                unsigned gC = *(const unsigned*)(H1 + (((unsigned)sC << 7) | kb4));
                unsigned gD = *(const unsigned*)(H1 + (((unsigned)sD << 7) | kb4));
                unsigned gE = *(const unsigned*)(H1 + (((unsigned)sE << 7) | kb4));
                unsigned gF = *(const unsigned*)(H1 + (((unsigned)sF << 7) | kb4));
                unsigned gG = *(const unsigned*)(H1 + (((unsigned)sG << 7) | kb4));
                unsigned gH = *(const unsigned*)(H1 + (((unsigned)sH << 7) | kb4));
                f32x2 t0, t1;
                t0 = __builtin_amdgcn_cvt_pk_f32_fp8((int)gA, false);
                t1 = __builtin_amdgcn_cvt_pk_f32_fp8((int)gA, true);
                acc01.x = fmaf(t0.x, vA, acc01.x); acc01.y = fmaf(t0.y, vA, acc01.y);
                acc23.x = fmaf(t1.x, vA, acc23.x); acc23.y = fmaf(t1.y, vA, acc23.y);
                t0 = __builtin_amdgcn_cvt_pk_f32_fp8((int)gB, false);
                t1 = __builtin_amdgcn_cvt_pk_f32_fp8((int)gB, true);
                acc01.x = fmaf(t0.x, vB, acc01.x); acc01.y = fmaf(t0.y, vB, acc01.y);
                acc23.x = fmaf(t1.x, vB, acc23.x); acc23.y = fmaf(t1.y, vB, acc23.y);
                t0 = __builtin_amdgcn_cvt_pk_f32_fp8((int)gC, false);
                t1 = __builtin_amdgcn_cvt_pk_f32_fp8((int)gC, true);
                acc01.x = fmaf(t0.x, vC, acc01.x); acc01.y = fmaf(t0.y, vC, acc01.y);
                acc23.x = fmaf(t1.x, vC, acc23.x); acc23.y = fmaf(t1.y, vC, acc23.y);
                t0 = __builtin_amdgcn_cvt_pk_f32_fp8((int)gD, false);
                t1 = __builtin_amdgcn_cvt_pk_f32_fp8((int)gD, true);
                acc01.x = fmaf(t0.x, vD, acc01.x); acc01.y = fmaf(t0.y, vD, acc01.y);
                acc23.x = fmaf(t1.x, vD, acc23.x); acc23.y = fmaf(t1.y, vD, acc23.y);
                t0 = __builtin_amdgcn_cvt_pk_f32_fp8((int)gE, false);
                t1 = __builtin_amdgcn_cvt_pk_f32_fp8((int)gE, true);
                acc01.x = fmaf(t0.x, vE, acc01.x); acc01.y = fmaf(t0.y, vE, acc01.y);
                acc23.x = fmaf(t1.x, vE, acc23.x); acc23.y = fmaf(t1.y, vE, acc23.y);
                t0 = __builtin_amdgcn_cvt_pk_f32_fp8((int)gF, false);
                t1 = __builtin_amdgcn_cvt_pk_f32_fp8((int)gF, true);
                acc01.x = fmaf(t0.x, vF, acc01.x); acc01.y = fmaf(t0.y, vF, acc01.y);
                acc23.x = fmaf(t1.x, vF, acc23.x); acc23.y = fmaf(t1.y, vF, acc23.y);
                t0 = __builtin_amdgcn_cvt_pk_f32_fp8((int)gG, false);
                t1 = __builtin_amdgcn_cvt_pk_f32_fp8((int)gG, true);
                acc01.x = fmaf(t0.x, vG, acc01.x); acc01.y = fmaf(t0.y, vG, acc01.y);
                acc23.x = fmaf(t1.x, vG, acc23.x); acc23.y = fmaf(t1.y, vG, acc23.y);
                t0 = __builtin_amdgcn_cvt_pk_f32_fp8((int)gH, false);
                t1 = __builtin_amdgcn_cvt_pk_f32_fp8((int)gH, true);
                acc01.x = fmaf(t0.x, vH, acc01.x); acc01.y = fmaf(t0.y, vH, acc01.y);
                acc23.x = fmaf(t1.x, vH, acc23.x); acc23.y = fmaf(t1.y, vH, acc23.y);
            }
        }
        // combine halves
        acc01.x += __shfl_xor(acc01.x, 32);
        acc01.y += __shfl_xor(acc01.y, 32);
        acc23.x += __shfl_xor(acc23.x, 32);
        acc23.y += __shfl_xor(acc23.y, 32);
        if (half == 0) {
            int p0 = li * 4;
            int f0 = ((p0 & 7) << 4) | (p0 >> 3);
            int f1 = (((p0 + 1) & 7) << 4) | ((p0 + 1) >> 3);
            int f2 = (((p0 + 2) & 7) << 4) | ((p0 + 2) >> 3);
            int f3 = (((p0 + 3) & 7) << 4) | ((p0 + 3) >> 3);
            f32x4 a;
            a[0] = fmaxf(fmaf(acc01.x, di, b1[f0]), 0.f);
            a[1] = fmaxf(fmaf(acc01.y, di, b1[f1]), 0.f);
            a[2] = fmaxf(fmaf(acc23.x, di, b1[f2]), 0.f);
            a[3] = fmaxf(fmaf(acc23.y, di, b1[f3]), 0.f);
            a_lds4[wave][li] = a;
        }
    }
    __syncthreads();
    if (d < N) {
        int c = lane & 15, kg = lane >> 4;
        const float* a_ldsf = (const float*)a_lds4[wave];
        const float* w2b = W2 + kg * 64 + c;
        float p = 0.f;
#pragma unroll
        for (int i = 0; i < 32; i++) {
            int w2off = ((i & 7) << 8) + ((i >> 3) << 4);
            p = fmaf(a_ldsf[kg * 32 + i], w2b[w2off], p);
        }
        p += __shfl_xor(p, 16);
        p += __shfl_xor(p, 32);
        if (lane < 16) H2[(size_t)d * NCLS + c] = f2bf(p * di);
    }
}

// ---------------- agg2 + log_softmax: 8 lanes/node, 2 classes/lane, 16-padded lists ----------------
__global__ __launch_bounds__(256, 8) void agg2_kernel(const unsigned short* __restrict__ H2,
                                                      const int* __restrict__ rowInfo,
                                                      const int* __restrict__ col,
                                                      const float* __restrict__ dinv,
                                                      const float* __restrict__ b2,
                                                      float* __restrict__ OUT, int N) {
    int tid = threadIdx.x;
    int g = tid >> 3, q = tid & 7;
    int d = blockIdx.x * 32 + g;
    if (d >= N) return;
    unsigned cb = (unsigned)q * 4;
    const char* H2b = (const char*)H2;
    float di = dinv[d];
    unsigned u = *(const unsigned*)(H2b + (((unsigned)d << 5) | cb));
    f32x2 acc; acc.x = bflo(u); acc.y = bfhi(u);
    int info = rowInfo[d];
    int jb = (info >> 12) << 4;
    int jend = jb + ((info & 0xFFF) << 4);
    for (int j = jb; j < jend; j += 8) {
        unsigned u0 = *(const unsigned*)(H2b + (((unsigned)col[j + 0] << 5) | cb));
        unsigned u1 = *(const unsigned*)(H2b + (((unsigned)col[j + 1] << 5) | cb));
        unsigned u2 = *(const unsigned*)(H2b + (((unsigned)col[j + 2] << 5) | cb));
        unsigned u3 = *(const unsigned*)(H2b + (((unsigned)col[j + 3] << 5) | cb));
        unsigned u4 = *(const unsigned*)(H2b + (((unsigned)col[j + 4] << 5) | cb));
        unsigned u5 = *(const unsigned*)(H2b + (((unsigned)col[j + 5] << 5) | cb));
        unsigned u6 = *(const unsigned*)(H2b + (((unsigned)col[j + 6] << 5) | cb));
        unsigned u7 = *(const unsigned*)(H2b + (((unsigned)col[j + 7] << 5) | cb));
        f32x2 v0; v0.x = bflo(u0); v0.y = bfhi(u0);
        f32x2 v1; v1.x = bflo(u1); v1.y = bfhi(u1);
        f32x2 v2; v2.x = bflo(u2); v2.y = bfhi(u2);
        f32x2 v3; v3.x = bflo(u3); v3.y = bfhi(u3);
        f32x2 v4; v4.x = bflo(u4); v4.y = bfhi(u4);
        f32x2 v5; v5.x = bflo(u5); v5.y = bfhi(u5);
        f32x2 v6; v6.x = bflo(u6); v6.y = bfhi(u6);
        f32x2 v7; v7.x = bflo(u7); v7.y = bfhi(u7);
        acc += ((v0 + v1) + (v2 + v3)) + ((v4 + v5) + (v6 + v7));
    }
    float l0 = fmaf(acc.x, di, b2[q * 2]);
    float l1 = fmaf(acc.y, di, b2[q * 2 + 1]);
    float m = fmaxf(l0, l1);
    m = fmaxf(m, __shfl_xor(m, 1, 8));
    m = fmaxf(m, __shfl_xor(m, 2, 8));
    m = fmaxf(m, __shfl_xor(m, 4, 8));
    float e = __expf(l0 - m) + __expf(l1 - m);
    e += __shfl_xor(e, 1, 8);
    e += __shfl_xor(e, 2, 8);
    e += __shfl_xor(e, 4, 8);
    float ls = __logf(e);
    float2 o; o.x = l0 - m - ls; o.y = l1 - m - ls;
    *(float2*)(OUT + ((size_t)d << 4) + q * 2) = o;
}

// ---------------- launch ----------------
extern "C" void kernel_launch(void* const* d_in, const int* in_sizes, int n_in,
                              void* d_out, int out_size, void* d_ws, size_t ws_size,
                              hipStream_t stream) {
    const float* x  = (const float*)d_in[0];
    const int*   ei = (const int*)d_in[1];
    const float* W1 = (const float*)d_in[2];
    const float* b1 = (const float*)d_in[3];
    const float* W2 = (const float*)d_in[4];
    const float* b2 = (const float*)d_in[5];
    float* out = (float*)d_out;

    const int N = in_sizes[0] / F_IN;    // 100000
    const int E = in_sizes[1] / 2;       // 1600000
    const int* src = ei;
    const int* dst = ei + E;
    const int nb = (N + (1 << BSH) - 1) >> BSH;   // 196 buckets

    // workspace layout (256B aligned)
    char* ws = (char*)d_ws;
    size_t off = 0;
    auto alloc = [&](size_t bytes) {
        size_t o = off;
        off += (bytes + 255) & ~(size_t)255;
        return (void*)(ws + o);
    };
    int*            bucketCur   = (int*)alloc(NBMAX * 4);
    int*            rowInfo     = (int*)alloc((size_t)N * 4);
    float*          dinv        = (float*)alloc((size_t)(N + 1) * 4);
    int*            colw        = (int*)alloc((size_t)NBMAX * PCAP * 4);
    unsigned short* w1f         = (unsigned short*)alloc(32768 * 2);
    unsigned short* h2          = (unsigned short*)alloc((size_t)(N + 1) * NCLS * 2);
    // pairs and h1 must NOT overlap (csr reads pairs while gemm writes h1 in same kernel)
    int2*           pairs       = (int2*)alloc((size_t)NBMAX * CAP * 8);
    unsigned char*  h1          = (unsigned char*)alloc((size_t)(N + 1) * DIM);
    (void)ws_size;

    const int gridE = (E + 8191) / 8192;   // 196

    init_kernel<<<128, 256, 0, stream>>>(W1, w1f, bucketCur,
                                         (unsigned*)(h1 + (size_t)N * DIM),
                                         (unsigned*)(h2 + (size_t)N * NCLS),
                                         dinv, N);
    part_kernel<<<gridE, 1024, 0, stream>>>(src, dst, bucketCur, pairs, E);
    csr_gemm_kernel<<<nb + (N + 63) / 64, 256, 0, stream>>>(pairs, bucketCur, rowInfo, dinv, colw,
                                                            x, w1f, h1, N, nb);
    agg1_kernel<<<(N + 3) / 4, 256, 0, stream>>>(h1, rowInfo, colw, dinv, b1, W2, h2, N);
    agg2_kernel<<<(N + 31) / 32, 256, 0, stream>>>(h2, rowInfo, colw, dinv, b2, out, N);
}

// Round 23
// 138.524 us; speedup vs baseline: 1.4965x; 1.0054x over previous
//
#include <hip/hip_runtime.h>
#include <hip/hip_bf16.h>

// ---------------- problem constants ----------------
#define F_IN   256
#define DIM    128
#define NCLS   16
#define BSH    9           // bucket shift: 512 nodes per bucket
#define NBMAX  256         // max buckets (N<=131072)
#define CAP    10240       // per-bucket pairs capacity (expected ~8.2K, +22 sigma)
#define PCAP   18432       // per-bucket padded col region (CAP + 16*512 pad headroom)

typedef short bf16x8 __attribute__((ext_vector_type(8)));
typedef float f32x4  __attribute__((ext_vector_type(4)));
typedef float f32x2  __attribute__((ext_vector_type(2)));

__device__ __forceinline__ unsigned short f2bf(float f) {
    union { float f; unsigned u; } v; v.f = f;
    unsigned r = v.u + 0x7fffu + ((v.u >> 16) & 1u);   // RNE
    return (unsigned short)(r >> 16);
}
__device__ __forceinline__ float bflo(unsigned v) { return __uint_as_float(v << 16); }
__device__ __forceinline__ float bfhi(unsigned v) { return __uint_as_float(v & 0xffff0000u); }

// ---------------- init: bucket cursors + W1 repack + dummy rows + dinv[N]=0 ----------------
__global__ void init_kernel(const float* __restrict__ W1, unsigned short* __restrict__ W1f,
                            int* __restrict__ bucketCur,
                            unsigned* __restrict__ h1dummy, unsigned* __restrict__ h2dummy,
                            float* __restrict__ dinv, int N) {
    int t = blockIdx.x * blockDim.x + threadIdx.x;
    if (blockIdx.x == 0) {
        bucketCur[threadIdx.x] = threadIdx.x * CAP;               // NBMAX = 256 = blockDim
        if (threadIdx.x < 32) h1dummy[threadIdx.x] = 0;           // 128 B fp8 dummy row
        else if (threadIdx.x < 40) h2dummy[threadIdx.x - 32] = 0; // 32 B bf16 dummy row
        else if (threadIdx.x == 40) dinv[N] = 0.f;                // dummy dinv -> pad edges = 0
    }
    if (t >= 8 * 32 * 16 * 8) return;
    int j = t & 7, c = (t >> 3) & 15, g = (t >> 7) & 31, f = t >> 12;
    W1f[t] = f2bf(W1[(g * 8 + j) * DIM + f * 16 + c]);
}

// ---------------- part: partition edges into per-bucket capacity regions ----------------
__global__ __launch_bounds__(1024) void part_kernel(const int* __restrict__ src,
                                                    const int* __restrict__ dst,
                                                    int* __restrict__ bucketCur,
                                                    int2* __restrict__ pairs, int E) {
    __shared__ int hist[NBMAX];
    __shared__ int pos[NBMAX];
    int t = threadIdx.x;
    int base = blockIdx.x * 8192;
    int s[8], d[8];
#pragma unroll
    for (int k = 0; k < 8; k++) {
        int i = base + k * 1024 + t;
        bool v = (i < E);
        s[k] = v ? src[i] : 0;
        d[k] = v ? dst[i] : -1;
    }
    if (t < NBMAX) hist[t] = 0;
    __syncthreads();
#pragma unroll
    for (int k = 0; k < 8; k++)
        if (d[k] >= 0) atomicAdd(&hist[d[k] >> BSH], 1);
    __syncthreads();
    if (t < NBMAX && hist[t]) pos[t] = atomicAdd(&bucketCur[t], hist[t]);
    __syncthreads();
#pragma unroll
    for (int k = 0; k < 8; k++)
        if (d[k] >= 0) {
            int p = atomicAdd(&pos[d[k] >> BSH], 1);
            pairs[p] = make_int2(s[k], d[k]);
        }
}

// ---------------- fat kernel: csr (blocks 0..nbCsr-1) || gemm1 (rest) ----------------
// csr: per-node counts, 16-padded local scan -> rowInfo/dinv, LDS-cursor scatter -> col.
// gemm: H1u = fp8(X @ W1) UNSCALED; W1f staged in LDS; X preloaded before the barrier.
__global__ __launch_bounds__(256) void csr_gemm_kernel(
        const int2* __restrict__ pairs, const int* __restrict__ bucketCur,
        int* __restrict__ rowInfo, float* __restrict__ dinv, int* __restrict__ col,
        const float* __restrict__ X, const unsigned short* __restrict__ W1f,
        unsigned char* __restrict__ H1, int N, int nbCsr) {
    __shared__ int sh[16384];   // 64KB: csr uses first 3KB; gemm uses all (W1f copy)
    int t = threadIdx.x;

    if (blockIdx.x < nbCsr) {
        // ---- CSR body ----
        int* cnt  = sh;
        int* part = sh + 512;
        int b = blockIdx.x;
        int n0 = b << BSH;
        int nn = N - n0; if (nn > 512) nn = 512;
        int in0 = b * CAP;
        int inEnd = bucketCur[b];
        int out0 = b * PCAP;

        cnt[t] = 0; cnt[t + 256] = 0;
        __syncthreads();
        for (int p = in0 + t; p < inEnd; p += 256)
            atomicAdd(&cnt[pairs[p].y - n0], 1);
        __syncthreads();

        int i0 = t * 2;
        int c0 = cnt[i0], c1 = cnt[i0 + 1];
        int p0 = (c0 + 15) & ~15, p1 = (c1 + 15) & ~15;   // pad to 16
        int tsum = p0 + p1;
        part[t] = tsum;
        __syncthreads();
        for (int off = 1; off < 256; off <<= 1) {
            int u = (t >= off) ? part[t - off] : 0;
            __syncthreads();
            part[t] += u;
            __syncthreads();
        }
        int run = out0 + part[t] - tsum;
        int e0 = run, e1 = e0 + p0;
        __syncthreads();
        // rowInfo = (start>>4)<<12 | nchunks16
        if (i0 + 0 < nn) { rowInfo[n0 + i0 + 0] = ((e0 >> 4) << 12) | (p0 >> 4); dinv[n0 + i0 + 0] = rsqrtf((float)(c0 + 1)); }
        if (i0 + 1 < nn) { rowInfo[n0 + i0 + 1] = ((e1 >> 4) << 12) | (p1 >> 4); dinv[n0 + i0 + 1] = rsqrtf((float)(c1 + 1)); }
        cnt[i0] = e0; cnt[i0 + 1] = e1;    // cursors
        __syncthreads();

        for (int p = in0 + t; p < inEnd; p += 256) {
            int2 e = pairs[p];
            int q = atomicAdd(&cnt[e.y - n0], 1);
            col[q] = e.x;
        }
        __syncthreads();
        if (i0 + 0 < nn) for (int q = c0; q < p0; q++) col[e0 + q] = N;   // dummy pad
        if (i0 + 1 < nn) for (int q = c1; q < p1; q++) col[e1 + q] = N;
    } else {
        // ---- GEMM body: 16 rows/wave, 64 rows/block ----
        int gb = blockIdx.x - nbCsr;
        int wm = t >> 6, l = t & 63;
        int lr = l & 15, lg = l >> 4;
        int bm = gb * 64 + wm * 16;

        int r = bm + lr;
        r = (r < N) ? r : (N - 1);
        const float* xp = X + (size_t)r * F_IN + lg * 8;

        // issue all 16 X loads BEFORE the staging barrier
        float4 u[16];
#pragma unroll
        for (int s = 0; s < 8; s++) {
            u[2 * s + 0] = *(const float4*)(xp + s * 32);
            u[2 * s + 1] = *(const float4*)(xp + s * 32 + 4);
        }

        // stage entire repacked W1f (64KB) into LDS: 16 x uint4 per thread
        uint4* wv = (uint4*)sh;
        const uint4* wg = (const uint4*)W1f;
#pragma unroll
        for (int i = 0; i < 16; i++) wv[t + i * 256] = wg[t + i * 256];
        __syncthreads();
        const unsigned short* w1s = (const unsigned short*)sh;

        f32x4 acc[8];
#pragma unroll
        for (int f = 0; f < 8; f++) acc[f] = (f32x4){0.f, 0.f, 0.f, 0.f};

#pragma unroll
        for (int s = 0; s < 8; s++) {            // k-step of 32, X in regs, W1f in LDS
            float4 u0 = u[2 * s + 0];
            float4 u1 = u[2 * s + 1];
            bf16x8 a;
            a[0] = (short)f2bf(u0.x); a[1] = (short)f2bf(u0.y);
            a[2] = (short)f2bf(u0.z); a[3] = (short)f2bf(u0.w);
            a[4] = (short)f2bf(u1.x); a[5] = (short)f2bf(u1.y);
            a[6] = (short)f2bf(u1.z); a[7] = (short)f2bf(u1.w);
#pragma unroll
            for (int f = 0; f < 8; f++) {
                bf16x8 b = *(const bf16x8*)(w1s + ((((f * 32 + s * 4 + lg) * 16) + lr) << 3));
                acc[f] = __builtin_amdgcn_mfma_f32_16x16x32_bf16(a, b, acc[f], 0, 0, 0);
            }
        }
#pragma unroll
        for (int rr = 0; rr < 4; rr++) {
            int row = bm + lg * 4 + rr;
            if (row < N) {
                int w0 = __builtin_amdgcn_cvt_pk_fp8_f32(acc[0][rr], acc[1][rr], 0, false);
                w0 = __builtin_amdgcn_cvt_pk_fp8_f32(acc[2][rr], acc[3][rr], w0, true);
                int w1 = __builtin_amdgcn_cvt_pk_fp8_f32(acc[4][rr], acc[5][rr], 0, false);
                w1 = __builtin_amdgcn_cvt_pk_fp8_f32(acc[6][rr], acc[7][rr], w1, true);
                uint2 pk; pk.x = (unsigned)w0; pk.y = (unsigned)w1;
                *(uint2*)(H1 + ((size_t)row << 7) + lr * 8) = pk;
            }
        }
    }
}

// ---------------- agg1 fused: sum(dv_s * H1u[s]) -> *di + b1 -> relu -> @W2 -> *di -> H2(bf16) ----------------
// one wave per dst node; lanes 0-31 edge A's row (dword = 4 fp8), lanes 32-63 edge B's row.
// Rows 16-padded with dummy node N (dinv[N]=0). 8 pair-gathers in flight.
// Accumulation in PACKED f32x2 math (v_pk_fma_f32): 2 pk_fma instead of 4 scalar fma per pair.
__global__ __launch_bounds__(256, 8) void agg1_kernel(const unsigned char* __restrict__ H1,
                                                      const int* __restrict__ rowInfo,
                                                      const int* __restrict__ col,
                                                      const float* __restrict__ dinv,
                                                      const float* __restrict__ b1,
                                                      const float* __restrict__ W2,
                                                      unsigned short* __restrict__ H2, int N) {
    __shared__ f32x4 a_lds4[4][32];
    int tid = threadIdx.x;
    int wave = tid >> 6, lane = tid & 63;
    int d = blockIdx.x * 4 + wave;
    int half = lane >> 5;
    int li = lane & 31;
    unsigned kb4 = (unsigned)li * 4;

    float di = 0.f;
    if (d < N) {
        di = dinv[d];
        unsigned sg = *(const unsigned*)(H1 + (((unsigned)d << 7) | kb4));   // self row (unscaled)
        if (half) sg = 0u;
        f32x2 dsp = {di, di};
        f32x2 acc01 = __builtin_amdgcn_cvt_pk_f32_fp8((int)sg, false) * dsp;
        f32x2 acc23 = __builtin_amdgcn_cvt_pk_f32_fp8((int)sg, true) * dsp;

        int info = rowInfo[d];
        int jb = (info >> 12) << 4;
        int jend = jb + ((info & 0xFFF) << 4);
        for (int j0 = jb; j0 < jend; j0 += 64) {
            int cnt = jend - j0; if (cnt > 64) cnt = 64;   // multiple of 16
            int eidx = col[j0 + lane];         // 64 edges: one VMEM
            // clamp: tail lanes may read uninitialized (poison) col at bucket tails
            if ((unsigned)eidx > (unsigned)N) eidx = N;
            float dv = dinv[eidx];             // 64 dinv: one VMEM gather (dinv[N]=0)
            for (int kk = 0; kk < cnt; kk += 16) {         // 8 pair-gathers in flight
                int sA = __shfl(eidx, kk + 0 + half),  sB = __shfl(eidx, kk + 2 + half);
                int sC = __shfl(eidx, kk + 4 + half),  sD = __shfl(eidx, kk + 6 + half);
                int sE = __shfl(eidx, kk + 8 + half),  sF = __shfl(eidx, kk + 10 + half);
                int sG = __shfl(eidx, kk + 12 + half), sH = __shfl(eidx, kk + 14 + half);
                float vA = __shfl(dv, kk + 0 + half),  vB = __shfl(dv, kk + 2 + half);
                float vC = __shfl(dv, kk + 4 + half),  vD = __shfl(dv, kk + 6 + half);
                float vE = __shfl(dv, kk + 8 + half),  vF = __shfl(dv, kk + 10 + half);
                float vG = __shfl(dv, kk + 12 + half), vH = __shfl(dv, kk + 14 + half);
                unsigned gA = *(const unsigned*)(H1 + (((unsigned)sA << 7) | kb4));
                unsigned gB = *(const unsigned*)(H1 + (((unsigned)sB << 7) | kb4));
                unsigned gC = *(const unsigned*)(H1 + (((unsigned)sC << 7) | kb4));
                unsigned gD = *(const unsigned*)(H1 + (((unsigned)sD << 7) | kb4));
                unsigned gE = *(const unsigned*)(H1 + (((unsigned)sE << 7) | kb4));
                unsigned gF = *(const unsigned*)(H1 + (((unsigned)sF << 7) | kb4));
                unsigned gG = *(const unsigned*)(H1 + (((unsigned)sG << 7) | kb4));
                unsigned gH = *(const unsigned*)(H1 + (((unsigned)sH << 7) | kb4));
                f32x2 wA = {vA, vA}, wB = {vB, vB}, wC = {vC, vC}, wD = {vD, vD};
                f32x2 wE = {vE, vE}, wF = {vF, vF}, wG = {vG, vG}, wH = {vH, vH};
                acc01 += __builtin_amdgcn_cvt_pk_f32_fp8((int)gA, false) * wA;
                acc23 += __builtin_amdgcn_cvt_pk_f32_fp8((int)gA, true)  * wA;
                acc01 += __builtin_amdgcn_cvt_pk_f32_fp8((int)gB, false) * wB;
                acc23 += __builtin_amdgcn_cvt_pk_f32_fp8((int)gB, true)  * wB;
                acc01 += __builtin_amdgcn_cvt_pk_f32_fp8((int)gC, false) * wC;
                acc23 += __builtin_amdgcn_cvt_pk_f32_fp8((int)gC, true)  * wC;
                acc01 += __builtin_amdgcn_cvt_pk_f32_fp8((int)gD, false) * wD;
                acc23 += __builtin_amdgcn_cvt_pk_f32_fp8((int)gD, true)  * wD;
                acc01 += __builtin_amdgcn_cvt_pk_f32_fp8((int)gE, false) * wE;
                acc23 += __builtin_amdgcn_cvt_pk_f32_fp8((int)gE, true)  * wE;
                acc01 += __builtin_amdgcn_cvt_pk_f32_fp8((int)gF, false) * wF;
                acc23 += __builtin_amdgcn_cvt_pk_f32_fp8((int)gF, true)  * wF;
                acc01 += __builtin_amdgcn_cvt_pk_f32_fp8((int)gG, false) * wG;
                acc23 += __builtin_amdgcn_cvt_pk_f32_fp8((int)gG, true)  * wG;
                acc01 += __builtin_amdgcn_cvt_pk_f32_fp8((int)gH, false) * wH;
                acc23 += __builtin_amdgcn_cvt_pk_f32_fp8((int)gH, true)  * wH;
            }
        }
        // combine halves
        acc01.x += __shfl_xor(acc01.x, 32);
        acc01.y += __shfl_xor(acc01.y, 32);
        acc23.x += __shfl_xor(acc23.x, 32);
        acc23.y += __shfl_xor(acc23.y, 32);
        if (half == 0) {
            int p0 = li * 4;
            int f0 = ((p0 & 7) << 4) | (p0 >> 3);
            int f1 = (((p0 + 1) & 7) << 4) | ((p0 + 1) >> 3);
            int f2 = (((p0 + 2) & 7) << 4) | ((p0 + 2) >> 3);
            int f3 = (((p0 + 3) & 7) << 4) | ((p0 + 3) >> 3);
            f32x4 a;
            a[0] = fmaxf(fmaf(acc01.x, di, b1[f0]), 0.f);
            a[1] = fmaxf(fmaf(acc01.y, di, b1[f1]), 0.f);
            a[2] = fmaxf(fmaf(acc23.x, di, b1[f2]), 0.f);
            a[3] = fmaxf(fmaf(acc23.y, di, b1[f3]), 0.f);
            a_lds4[wave][li] = a;
        }
    }
    __syncthreads();
    if (d < N) {
        int c = lane & 15, kg = lane >> 4;
        const float* a_ldsf = (const float*)a_lds4[wave];
        const float* w2b = W2 + kg * 64 + c;
        float p = 0.f;
#pragma unroll
        for (int i = 0; i < 32; i++) {
            int w2off = ((i & 7) << 8) + ((i >> 3) << 4);
            p = fmaf(a_ldsf[kg * 32 + i], w2b[w2off], p);
        }
        p += __shfl_xor(p, 16);
        p += __shfl_xor(p, 32);
        if (lane < 16) H2[(size_t)d * NCLS + c] = f2bf(p * di);
    }
}

// ---------------- agg2 + log_softmax: 8 lanes/node, 2 classes/lane, 16-padded lists ----------------
__global__ __launch_bounds__(256, 8) void agg2_kernel(const unsigned short* __restrict__ H2,
                                                      const int* __restrict__ rowInfo,
                                                      const int* __restrict__ col,
                                                      const float* __restrict__ dinv,
                                                      const float* __restrict__ b2,
                                                      float* __restrict__ OUT, int N) {
    int tid = threadIdx.x;
    int g = tid >> 3, q = tid & 7;
    int d = blockIdx.x * 32 + g;
    if (d >= N) return;
    unsigned cb = (unsigned)q * 4;
    const char* H2b = (const char*)H2;
    float di = dinv[d];
    unsigned u = *(const unsigned*)(H2b + (((unsigned)d << 5) | cb));
    f32x2 acc; acc.x = bflo(u); acc.y = bfhi(u);
    int info = rowInfo[d];
    int jb = (info >> 12) << 4;
    int jend = jb + ((info & 0xFFF) << 4);
    for (int j = jb; j < jend; j += 8) {
        unsigned u0 = *(const unsigned*)(H2b + (((unsigned)col[j + 0] << 5) | cb));
        unsigned u1 = *(const unsigned*)(H2b + (((unsigned)col[j + 1] << 5) | cb));
        unsigned u2 = *(const unsigned*)(H2b + (((unsigned)col[j + 2] << 5) | cb));
        unsigned u3 = *(const unsigned*)(H2b + (((unsigned)col[j + 3] << 5) | cb));
        unsigned u4 = *(const unsigned*)(H2b + (((unsigned)col[j + 4] << 5) | cb));
        unsigned u5 = *(const unsigned*)(H2b + (((unsigned)col[j + 5] << 5) | cb));
        unsigned u6 = *(const unsigned*)(H2b + (((unsigned)col[j + 6] << 5) | cb));
        unsigned u7 = *(const unsigned*)(H2b + (((unsigned)col[j + 7] << 5) | cb));
        f32x2 v0; v0.x = bflo(u0); v0.y = bfhi(u0);
        f32x2 v1; v1.x = bflo(u1); v1.y = bfhi(u1);
        f32x2 v2; v2.x = bflo(u2); v2.y = bfhi(u2);
        f32x2 v3; v3.x = bflo(u3); v3.y = bfhi(u3);
        f32x2 v4; v4.x = bflo(u4); v4.y = bfhi(u4);
        f32x2 v5; v5.x = bflo(u5); v5.y = bfhi(u5);
        f32x2 v6; v6.x = bflo(u6); v6.y = bfhi(u6);
        f32x2 v7; v7.x = bflo(u7); v7.y = bfhi(u7);
        acc += ((v0 + v1) + (v2 + v3)) + ((v4 + v5) + (v6 + v7));
    }
    float l0 = fmaf(acc.x, di, b2[q * 2]);
    float l1 = fmaf(acc.y, di, b2[q * 2 + 1]);
    float m = fmaxf(l0, l1);
    m = fmaxf(m, __shfl_xor(m, 1, 8));
    m = fmaxf(m, __shfl_xor(m, 2, 8));
    m = fmaxf(m, __shfl_xor(m, 4, 8));
    float e = __expf(l0 - m) + __expf(l1 - m);
    e += __shfl_xor(e, 1, 8);
    e += __shfl_xor(e, 2, 8);
    e += __shfl_xor(e, 4, 8);
    float ls = __logf(e);
    float2 o; o.x = l0 - m - ls; o.y = l1 - m - ls;
    *(float2*)(OUT + ((size_t)d << 4) + q * 2) = o;
}

// ---------------- launch ----------------
extern "C" void kernel_launch(void* const* d_in, const int* in_sizes, int n_in,
                              void* d_out, int out_size, void* d_ws, size_t ws_size,
                              hipStream_t stream) {
    const float* x  = (const float*)d_in[0];
    const int*   ei = (const int*)d_in[1];
    const float* W1 = (const float*)d_in[2];
    const float* b1 = (const float*)d_in[3];
    const float* W2 = (const float*)d_in[4];
    const float* b2 = (const float*)d_in[5];
    float* out = (float*)d_out;

    const int N = in_sizes[0] / F_IN;    // 100000
    const int E = in_sizes[1] / 2;       // 1600000
    const int* src = ei;
    const int* dst = ei + E;
    const int nb = (N + (1 << BSH) - 1) >> BSH;   // 196 buckets

    // workspace layout (256B aligned)
    char* ws = (char*)d_ws;
    size_t off = 0;
    auto alloc = [&](size_t bytes) {
        size_t o = off;
        off += (bytes + 255) & ~(size_t)255;
        return (void*)(ws + o);
    };
    int*            bucketCur   = (int*)alloc(NBMAX * 4);
    int*            rowInfo     = (int*)alloc((size_t)N * 4);
    float*          dinv        = (float*)alloc((size_t)(N + 1) * 4);
    int*            colw        = (int*)alloc((size_t)NBMAX * PCAP * 4);
    unsigned short* w1f         = (unsigned short*)alloc(32768 * 2);
    unsigned short* h2          = (unsigned short*)alloc((size_t)(N + 1) * NCLS * 2);
    // pairs and h1 must NOT overlap (csr reads pairs while gemm writes h1 in same kernel)
    int2*           pairs       = (int2*)alloc((size_t)NBMAX * CAP * 8);
    unsigned char*  h1          = (unsigned char*)alloc((size_t)(N + 1) * DIM);
    (void)ws_size;

    const int gridE = (E + 8191) / 8192;   // 196

    init_kernel<<<128, 256, 0, stream>>>(W1, w1f, bucketCur,
                                         (unsigned*)(h1 + (size_t)N * DIM),
                                         (unsigned*)(h2 + (size_t)N * NCLS),
                                         dinv, N);
    part_kernel<<<gridE, 1024, 0, stream>>>(src, dst, bucketCur, pairs, E);
    csr_gemm_kernel<<<nb + (N + 63) / 64, 256, 0, stream>>>(pairs, bucketCur, rowInfo, dinv, colw,
                                                            x, w1f, h1, N, nb);
    agg1_kernel<<<(N + 3) / 4, 256, 0, stream>>>(h1, rowInfo, colw, dinv, b1, W2, h2, N);
    agg2_kernel<<<(N + 31) / 32, 256, 0, stream>>>(h2, rowInfo, colw, dinv, b2, out, N);
}

// Round 24
// 137.693 us; speedup vs baseline: 1.5056x; 1.0060x over previous
//
#include <hip/hip_runtime.h>
#include <hip/hip_bf16.h>

// ---------------- problem constants ----------------
#define F_IN   256
#define DIM    128
#define NCLS   16
#define BSH    9           // bucket shift: 512 nodes per bucket
#define NBMAX  256         // max buckets (N<=131072)
#define CAP    10240       // per-bucket pairs capacity (expected ~8.2K, +22 sigma)
#define PCAP   18432       // per-bucket padded col region (CAP + 16*512 pad headroom)

typedef short bf16x8 __attribute__((ext_vector_type(8)));
typedef float f32x4  __attribute__((ext_vector_type(4)));
typedef float f32x2  __attribute__((ext_vector_type(2)));

__device__ __forceinline__ unsigned short f2bf(float f) {
    union { float f; unsigned u; } v; v.f = f;
    unsigned r = v.u + 0x7fffu + ((v.u >> 16) & 1u);   // RNE
    return (unsigned short)(r >> 16);
}
__device__ __forceinline__ float bflo(unsigned v) { return __uint_as_float(v << 16); }
__device__ __forceinline__ float bfhi(unsigned v) { return __uint_as_float(v & 0xffff0000u); }

// ---------------- init: bucket cursors + W1 repack + dummy rows + dinv[N]=0 ----------------
__global__ void init_kernel(const float* __restrict__ W1, unsigned short* __restrict__ W1f,
                            int* __restrict__ bucketCur,
                            unsigned* __restrict__ h1dummy, unsigned* __restrict__ h2dummy,
                            float* __restrict__ dinv, int N) {
    int t = blockIdx.x * blockDim.x + threadIdx.x;
    if (blockIdx.x == 0) {
        bucketCur[threadIdx.x] = threadIdx.x * CAP;               // NBMAX = 256 = blockDim
        if (threadIdx.x < 32) h1dummy[threadIdx.x] = 0;           // 128 B fp8 dummy row
        else if (threadIdx.x < 40) h2dummy[threadIdx.x - 32] = 0; // 32 B bf16 dummy row
        else if (threadIdx.x == 40) dinv[N] = 0.f;                // dummy dinv -> pad edges = 0
    }
    if (t >= 8 * 32 * 16 * 8) return;
    int j = t & 7, c = (t >> 3) & 15, g = (t >> 7) & 31, f = t >> 12;
    W1f[t] = f2bf(W1[(g * 8 + j) * DIM + f * 16 + c]);
}

// ---------------- part: partition edges into per-bucket capacity regions ----------------
__global__ __launch_bounds__(1024) void part_kernel(const int* __restrict__ src,
                                                    const int* __restrict__ dst,
                                                    int* __restrict__ bucketCur,
                                                    int2* __restrict__ pairs, int E) {
    __shared__ int hist[NBMAX];
    __shared__ int pos[NBMAX];
    int t = threadIdx.x;
    int base = blockIdx.x * 8192;
    int s[8], d[8];
#pragma unroll
    for (int k = 0; k < 8; k++) {
        int i = base + k * 1024 + t;
        bool v = (i < E);
        s[k] = v ? src[i] : 0;
        d[k] = v ? dst[i] : -1;
    }
    if (t < NBMAX) hist[t] = 0;
    __syncthreads();
#pragma unroll
    for (int k = 0; k < 8; k++)
        if (d[k] >= 0) atomicAdd(&hist[d[k] >> BSH], 1);
    __syncthreads();
    if (t < NBMAX && hist[t]) pos[t] = atomicAdd(&bucketCur[t], hist[t]);
    __syncthreads();
#pragma unroll
    for (int k = 0; k < 8; k++)
        if (d[k] >= 0) {
            int p = atomicAdd(&pos[d[k] >> BSH], 1);
            pairs[p] = make_int2(s[k], d[k]);
        }
}

// ---------------- fat kernel (512 threads): csr (blocks 0..nbCsr-1) || gemm1 (rest) ----------------
// csr: 1 node/thread, 512-wide padded scan -> rowInfo/dinv, LDS-cursor scatter -> col.
// gemm: 8 waves x 16 rows = 128 rows/block; W1f staged in LDS (64KB); X preloaded first.
__global__ __launch_bounds__(512) void csr_gemm_kernel(
        const int2* __restrict__ pairs, const int* __restrict__ bucketCur,
        int* __restrict__ rowInfo, float* __restrict__ dinv, int* __restrict__ col,
        const float* __restrict__ X, const unsigned short* __restrict__ W1f,
        unsigned char* __restrict__ H1, int N, int nbCsr) {
    __shared__ int sh[16384];   // 64KB: csr uses first 4KB (cnt[512]+part[512]); gemm uses all
    int t = threadIdx.x;

    if (blockIdx.x < nbCsr) {
        // ---- CSR body: 512 threads, one node each ----
        int* cnt  = sh;          // [512]
        int* part = sh + 512;    // [512]
        int b = blockIdx.x;
        int n0 = b << BSH;
        int nn = N - n0; if (nn > 512) nn = 512;
        int in0 = b * CAP;
        int inEnd = bucketCur[b];
        int out0 = b * PCAP;

        cnt[t] = 0;
        __syncthreads();
        for (int p = in0 + t; p < inEnd; p += 512)
            atomicAdd(&cnt[pairs[p].y - n0], 1);
        __syncthreads();

        int c0 = cnt[t];
        int p0 = (c0 + 15) & ~15;          // pad to 16
        part[t] = p0;
        __syncthreads();
        for (int off = 1; off < 512; off <<= 1) {
            int u = (t >= off) ? part[t - off] : 0;
            __syncthreads();
            part[t] += u;
            __syncthreads();
        }
        int e0 = out0 + part[t] - p0;      // padded exclusive start for node t
        __syncthreads();
        if (t < nn) {
            rowInfo[n0 + t] = ((e0 >> 4) << 12) | (p0 >> 4);
            dinv[n0 + t] = rsqrtf((float)(c0 + 1));
        }
        cnt[t] = e0;                        // cursor
        __syncthreads();

        for (int p = in0 + t; p < inEnd; p += 512) {
            int2 e = pairs[p];
            int q = atomicAdd(&cnt[e.y - n0], 1);
            col[q] = e.x;
        }
        __syncthreads();
        if (t < nn) for (int q = c0; q < p0; q++) col[e0 + q] = N;   // dummy pad
    } else {
        // ---- GEMM body: 8 waves x 16 rows = 128 rows/block ----
        int gb = blockIdx.x - nbCsr;
        int wm = t >> 6, l = t & 63;
        int lr = l & 15, lg = l >> 4;
        int bm = gb * 128 + wm * 16;

        int r = bm + lr;
        r = (r < N) ? r : (N - 1);
        const float* xp = X + (size_t)r * F_IN + lg * 8;

        // issue all 16 X loads BEFORE the staging barrier
        float4 u[16];
#pragma unroll
        for (int s = 0; s < 8; s++) {
            u[2 * s + 0] = *(const float4*)(xp + s * 32);
            u[2 * s + 1] = *(const float4*)(xp + s * 32 + 4);
        }

        // stage entire repacked W1f (64KB) into LDS: 8 x uint4 per thread (512 thr)
        uint4* wv = (uint4*)sh;
        const uint4* wg = (const uint4*)W1f;
#pragma unroll
        for (int i = 0; i < 8; i++) wv[t + i * 512] = wg[t + i * 512];
        __syncthreads();
        const unsigned short* w1s = (const unsigned short*)sh;

        f32x4 acc[8];
#pragma unroll
        for (int f = 0; f < 8; f++) acc[f] = (f32x4){0.f, 0.f, 0.f, 0.f};

#pragma unroll
        for (int s = 0; s < 8; s++) {            // k-step of 32, X in regs, W1f in LDS
            float4 u0 = u[2 * s + 0];
            float4 u1 = u[2 * s + 1];
            bf16x8 a;
            a[0] = (short)f2bf(u0.x); a[1] = (short)f2bf(u0.y);
            a[2] = (short)f2bf(u0.z); a[3] = (short)f2bf(u0.w);
            a[4] = (short)f2bf(u1.x); a[5] = (short)f2bf(u1.y);
            a[6] = (short)f2bf(u1.z); a[7] = (short)f2bf(u1.w);
#pragma unroll
            for (int f = 0; f < 8; f++) {
                bf16x8 b = *(const bf16x8*)(w1s + ((((f * 32 + s * 4 + lg) * 16) + lr) << 3));
                acc[f] = __builtin_amdgcn_mfma_f32_16x16x32_bf16(a, b, acc[f], 0, 0, 0);
            }
        }
#pragma unroll
        for (int rr = 0; rr < 4; rr++) {
            int row = bm + lg * 4 + rr;
            if (row < N) {
                int w0 = __builtin_amdgcn_cvt_pk_fp8_f32(acc[0][rr], acc[1][rr], 0, false);
                w0 = __builtin_amdgcn_cvt_pk_fp8_f32(acc[2][rr], acc[3][rr], w0, true);
                int w1 = __builtin_amdgcn_cvt_pk_fp8_f32(acc[4][rr], acc[5][rr], 0, false);
                w1 = __builtin_amdgcn_cvt_pk_fp8_f32(acc[6][rr], acc[7][rr], w1, true);
                uint2 pk; pk.x = (unsigned)w0; pk.y = (unsigned)w1;
                *(uint2*)(H1 + ((size_t)row << 7) + lr * 8) = pk;
            }
        }
    }
}

// ---------------- agg1 fused: sum(dv_s * H1u[s]) -> *di + b1 -> relu -> @W2 -> *di -> H2(bf16) ----------------
// one wave per dst node; lanes 0-31 edge A's row (dword = 4 fp8), lanes 32-63 edge B's row.
// Rows 16-padded with dummy node N (dinv[N]=0). 8 pair-gathers in flight.
__global__ __launch_bounds__(256, 8) void agg1_kernel(const unsigned char* __restrict__ H1,
                                                      const int* __restrict__ rowInfo,
                                                      const int* __restrict__ col,
                                                      const float* __restrict__ dinv,
                                                      const float* __restrict__ b1,
                                                      const float* __restrict__ W2,
                                                      unsigned short* __restrict__ H2, int N) {
    __shared__ f32x4 a_lds4[4][32];
    int tid = threadIdx.x;
    int wave = tid >> 6, lane = tid & 63;
    int d = blockIdx.x * 4 + wave;
    int half = lane >> 5;
    int li = lane & 31;
    unsigned kb4 = (unsigned)li * 4;

    float di = 0.f;
    if (d < N) {
        di = dinv[d];
        unsigned sg = *(const unsigned*)(H1 + (((unsigned)d << 7) | kb4));   // self row (unscaled)
        if (half) sg = 0u;
        f32x2 dsp = {di, di};
        f32x2 acc01 = __builtin_amdgcn_cvt_pk_f32_fp8((int)sg, false) * dsp;
        f32x2 acc23 = __builtin_amdgcn_cvt_pk_f32_fp8((int)sg, true) * dsp;

        int info = rowInfo[d];
        int jb = (info >> 12) << 4;
        int jend = jb + ((info & 0xFFF) << 4);
        for (int j0 = jb; j0 < jend; j0 += 64) {
            int cnt = jend - j0; if (cnt > 64) cnt = 64;   // multiple of 16
            int eidx = col[j0 + lane];         // 64 edges: one VMEM
            // clamp: tail lanes may read uninitialized (poison) col at bucket tails
            if ((unsigned)eidx > (unsigned)N) eidx = N;
            float dv = dinv[eidx];             // 64 dinv: one VMEM gather (dinv[N]=0)
            for (int kk = 0; kk < cnt; kk += 16) {         // 8 pair-gathers in flight
                int sA = __shfl(eidx, kk + 0 + half),  sB = __shfl(eidx, kk + 2 + half);
                int sC = __shfl(eidx, kk + 4 + half),  sD = __shfl(eidx, kk + 6 + half);
                int sE = __shfl(eidx, kk + 8 + half),  sF = __shfl(eidx, kk + 10 + half);
                int sG = __shfl(eidx, kk + 12 + half), sH = __shfl(eidx, kk + 14 + half);
                float vA = __shfl(dv, kk + 0 + half),  vB = __shfl(dv, kk + 2 + half);
                float vC = __shfl(dv, kk + 4 + half),  vD = __shfl(dv, kk + 6 + half);
                float vE = __shfl(dv, kk + 8 + half),  vF = __shfl(dv, kk + 10 + half);
                float vG = __shfl(dv, kk + 12 + half), vH = __shfl(dv, kk + 14 + half);
                unsigned gA = *(const unsigned*)(H1 + (((unsigned)sA << 7) | kb4));
                unsigned gB = *(const unsigned*)(H1 + (((unsigned)sB << 7) | kb4));
                unsigned gC = *(const unsigned*)(H1 + (((unsigned)sC << 7) | kb4));
                unsigned gD = *(const unsigned*)(H1 + (((unsigned)sD << 7) | kb4));
                unsigned gE = *(const unsigned*)(H1 + (((unsigned)sE << 7) | kb4));
                unsigned gF = *(const unsigned*)(H1 + (((unsigned)sF << 7) | kb4));
                unsigned gG = *(const unsigned*)(H1 + (((unsigned)sG << 7) | kb4));
                unsigned gH = *(const unsigned*)(H1 + (((unsigned)sH << 7) | kb4));
                f32x2 wA = {vA, vA}, wB = {vB, vB}, wC = {vC, vC}, wD = {vD, vD};
                f32x2 wE = {vE, vE}, wF = {vF, vF}, wG = {vG, vG}, wH = {vH, vH};
                acc01 += __builtin_amdgcn_cvt_pk_f32_fp8((int)gA, false) * wA;
                acc23 += __builtin_amdgcn_cvt_pk_f32_fp8((int)gA, true)  * wA;
                acc01 += __builtin_amdgcn_cvt_pk_f32_fp8((int)gB, false) * wB;
                acc23 += __builtin_amdgcn_cvt_pk_f32_fp8((int)gB, true)  * wB;
                acc01 += __builtin_amdgcn_cvt_pk_f32_fp8((int)gC, false) * wC;
                acc23 += __builtin_amdgcn_cvt_pk_f32_fp8((int)gC, true)  * wC;
                acc01 += __builtin_amdgcn_cvt_pk_f32_fp8((int)gD, false) * wD;
                acc23 += __builtin_amdgcn_cvt_pk_f32_fp8((int)gD, true)  * wD;
                acc01 += __builtin_amdgcn_cvt_pk_f32_fp8((int)gE, false) * wE;
                acc23 += __builtin_amdgcn_cvt_pk_f32_fp8((int)gE, true)  * wE;
                acc01 += __builtin_amdgcn_cvt_pk_f32_fp8((int)gF, false) * wF;
                acc23 += __builtin_amdgcn_cvt_pk_f32_fp8((int)gF, true)  * wF;
                acc01 += __builtin_amdgcn_cvt_pk_f32_fp8((int)gG, false) * wG;
                acc23 += __builtin_amdgcn_cvt_pk_f32_fp8((int)gG, true)  * wG;
                acc01 += __builtin_amdgcn_cvt_pk_f32_fp8((int)gH, false) * wH;
                acc23 += __builtin_amdgcn_cvt_pk_f32_fp8((int)gH, true)  * wH;
            }
        }
        // combine halves
        acc01.x += __shfl_xor(acc01.x, 32);
        acc01.y += __shfl_xor(acc01.y, 32);
        acc23.x += __shfl_xor(acc23.x, 32);
        acc23.y += __shfl_xor(acc23.y, 32);
        if (half == 0) {
            int p0 = li * 4;
            int f0 = ((p0 & 7) << 4) | (p0 >> 3);
            int f1 = (((p0 + 1) & 7) << 4) | ((p0 + 1) >> 3);
            int f2 = (((p0 + 2) & 7) << 4) | ((p0 + 2) >> 3);
            int f3 = (((p0 + 3) & 7) << 4) | ((p0 + 3) >> 3);
            f32x4 a;
            a[0] = fmaxf(fmaf(acc01.x, di, b1[f0]), 0.f);
            a[1] = fmaxf(fmaf(acc01.y, di, b1[f1]), 0.f);
            a[2] = fmaxf(fmaf(acc23.x, di, b1[f2]), 0.f);
            a[3] = fmaxf(fmaf(acc23.y, di, b1[f3]), 0.f);
            a_lds4[wave][li] = a;
        }
    }
    __syncthreads();
    if (d < N) {
        int c = lane & 15, kg = lane >> 4;
        const float* a_ldsf = (const float*)a_lds4[wave];
        const float* w2b = W2 + kg * 64 + c;
        float p = 0.f;
#pragma unroll
        for (int i = 0; i < 32; i++) {
            int w2off = ((i & 7) << 8) + ((i >> 3) << 4);
            p = fmaf(a_ldsf[kg * 32 + i], w2b[w2off], p);
        }
        p += __shfl_xor(p, 16);
        p += __shfl_xor(p, 32);
        if (lane < 16) H2[(size_t)d * NCLS + c] = f2bf(p * di);
    }
}

// ---------------- agg2 + log_softmax: 8 lanes/node, 2 classes/lane, 16-padded lists ----------------
__global__ __launch_bounds__(256, 8) void agg2_kernel(const unsigned short* __restrict__ H2,
                                                      const int* __restrict__ rowInfo,
                                                      const int* __restrict__ col,
                                                      const float* __restrict__ dinv,
                                                      const float* __restrict__ b2,
                                                      float* __restrict__ OUT, int N) {
    int tid = threadIdx.x;
    int g = tid >> 3, q = tid & 7;
    int d = blockIdx.x * 32 + g;
    if (d >= N) return;
    unsigned cb = (unsigned)q * 4;
    const char* H2b = (const char*)H2;
    float di = dinv[d];
    unsigned u = *(const unsigned*)(H2b + (((unsigned)d << 5) | cb));
    f32x2 acc; acc.x = bflo(u); acc.y = bfhi(u);
    int info = rowInfo[d];
    int jb = (info >> 12) << 4;
    int jend = jb + ((info & 0xFFF) << 4);
    for (int j = jb; j < jend; j += 8) {
        unsigned u0 = *(const unsigned*)(H2b + (((unsigned)col[j + 0] << 5) | cb));
        unsigned u1 = *(const unsigned*)(H2b + (((unsigned)col[j + 1] << 5) | cb));
        unsigned u2 = *(const unsigned*)(H2b + (((unsigned)col[j + 2] << 5) | cb));
        unsigned u3 = *(const unsigned*)(H2b + (((unsigned)col[j + 3] << 5) | cb));
        unsigned u4 = *(const unsigned*)(H2b + (((unsigned)col[j + 4] << 5) | cb));
        unsigned u5 = *(const unsigned*)(H2b + (((unsigned)col[j + 5] << 5) | cb));
        unsigned u6 = *(const unsigned*)(H2b + (((unsigned)col[j + 6] << 5) | cb));
        unsigned u7 = *(const unsigned*)(H2b + (((unsigned)col[j + 7] << 5) | cb));
        f32x2 v0; v0.x = bflo(u0); v0.y = bfhi(u0);
        f32x2 v1; v1.x = bflo(u1); v1.y = bfhi(u1);
        f32x2 v2; v2.x = bflo(u2); v2.y = bfhi(u2);
        f32x2 v3; v3.x = bflo(u3); v3.y = bfhi(u3);
        f32x2 v4; v4.x = bflo(u4); v4.y = bfhi(u4);
        f32x2 v5; v5.x = bflo(u5); v5.y = bfhi(u5);
        f32x2 v6; v6.x = bflo(u6); v6.y = bfhi(u6);
        f32x2 v7; v7.x = bflo(u7); v7.y = bfhi(u7);
        acc += ((v0 + v1) + (v2 + v3)) + ((v4 + v5) + (v6 + v7));
    }
    float l0 = fmaf(acc.x, di, b2[q * 2]);
    float l1 = fmaf(acc.y, di, b2[q * 2 + 1]);
    float m = fmaxf(l0, l1);
    m = fmaxf(m, __shfl_xor(m, 1, 8));
    m = fmaxf(m, __shfl_xor(m, 2, 8));
    m = fmaxf(m, __shfl_xor(m, 4, 8));
    float e = __expf(l0 - m) + __expf(l1 - m);
    e += __shfl_xor(e, 1, 8);
    e += __shfl_xor(e, 2, 8);
    e += __shfl_xor(e, 4, 8);
    float ls = __logf(e);
    float2 o; o.x = l0 - m - ls; o.y = l1 - m - ls;
    *(float2*)(OUT + ((size_t)d << 4) + q * 2) = o;
}

// ---------------- launch ----------------
extern "C" void kernel_launch(void* const* d_in, const int* in_sizes, int n_in,
                              void* d_out, int out_size, void* d_ws, size_t ws_size,
                              hipStream_t stream) {
    const float* x  = (const float*)d_in[0];
    const int*   ei = (const int*)d_in[1];
    const float* W1 = (const float*)d_in[2];
    const float* b1 = (const float*)d_in[3];
    const float* W2 = (const float*)d_in[4];
    const float* b2 = (const float*)d_in[5];
    float* out = (float*)d_out;

    const int N = in_sizes[0] / F_IN;    // 100000
    const int E = in_sizes[1] / 2;       // 1600000
    const int* src = ei;
    const int* dst = ei + E;
    const int nb = (N + (1 << BSH) - 1) >> BSH;   // 196 buckets

    // workspace layout (256B aligned)
    char* ws = (char*)d_ws;
    size_t off = 0;
    auto alloc = [&](size_t bytes) {
        size_t o = off;
        off += (bytes + 255) & ~(size_t)255;
        return (void*)(ws + o);
    };
    int*            bucketCur   = (int*)alloc(NBMAX * 4);
    int*            rowInfo     = (int*)alloc((size_t)N * 4);
    float*          dinv        = (float*)alloc((size_t)(N + 1) * 4);
    int*            colw        = (int*)alloc((size_t)NBMAX * PCAP * 4);
    unsigned short* w1f         = (unsigned short*)alloc(32768 * 2);
    unsigned short* h2          = (unsigned short*)alloc((size_t)(N + 1) * NCLS * 2);
    // pairs and h1 must NOT overlap (csr reads pairs while gemm writes h1 in same kernel)
    int2*           pairs       = (int2*)alloc((size_t)NBMAX * CAP * 8);
    unsigned char*  h1          = (unsigned char*)alloc((size_t)(N + 1) * DIM);
    (void)ws_size;

    const int gridE = (E + 8191) / 8192;   // 196

    init_kernel<<<128, 256, 0, stream>>>(W1, w1f, bucketCur,
                                         (unsigned*)(h1 + (size_t)N * DIM),
                                         (unsigned*)(h2 + (size_t)N * NCLS),
                                         dinv, N);
    part_kernel<<<gridE, 1024, 0, stream>>>(src, dst, bucketCur, pairs, E);
    csr_gemm_kernel<<<nb + (N + 127) / 128, 512, 0, stream>>>(pairs, bucketCur, rowInfo, dinv, colw,
                                                              x, w1f, h1, N, nb);
    agg1_kernel<<<(N + 3) / 4, 256, 0, stream>>>(h1, rowInfo, colw, dinv, b1, W2, h2, N);
    agg2_kernel<<<(N + 31) / 32, 256, 0, stream>>>(h2, rowInfo, colw, dinv, b2, out, N);
}